// Round 1
// 1281.064 us; speedup vs baseline: 1.1937x; 1.1937x over previous
//
#include <hip/hip_runtime.h>
#include <stdint.h>

typedef unsigned short u16;
typedef unsigned int   u32;

#define HW 65536   // 256*256

typedef __bf16 bf16x8 __attribute__((ext_vector_type(8)));
typedef float  f32x4  __attribute__((ext_vector_type(4)));

static __device__ __forceinline__ float bf2f(u16 h) {
    u32 u = ((u32)h) << 16;
    return __builtin_bit_cast(float, u);
}
static __device__ __forceinline__ u16 f2bf(float f) {
    u32 u = __builtin_bit_cast(u32, f);
    u += 0x7fffu + ((u >> 16) & 1u);   // RNE
    return (u16)(u >> 16);
}
static __device__ __forceinline__ void bf2x2(u32 u, float& a, float& b) {
    a = __builtin_bit_cast(float, u << 16);
    b = __builtin_bit_cast(float, u & 0xffff0000u);
}
static __device__ __forceinline__ f32x4 mfma16(bf16x8 a, bf16x8 b, f32x4 c) {
    return __builtin_amdgcn_mfma_f32_16x16x32_bf16(a, b, c, 0, 0, 0);
}

// ---------------------------------------------------------------------------
// K0a: relative position bias MLP: (961,2) -> (961,6)
// ---------------------------------------------------------------------------
static __device__ __forceinline__ void lnrelu11(float* p, const float* __restrict__ w,
                                                const float* __restrict__ b) {
    float m = 0.f;
    #pragma unroll
    for (int k = 0; k < 11; k++) m += p[k];
    m *= (1.0f / 11.0f);
    float v = 0.f;
    #pragma unroll
    for (int k = 0; k < 11; k++) { float d = p[k] - m; v = fmaf(d, d, v); }
    v *= (1.0f / 11.0f);
    float r = 1.0f / sqrtf(v + 1e-5f);
    #pragma unroll
    for (int k = 0; k < 11; k++) {
        float t = (p[k] - m) * r * w[k] + b[k];
        p[k] = t > 0.f ? t : 0.f;
    }
}

__global__ __launch_bounds__(1024) void k_pos(
    const float* __restrict__ pw, const float* __restrict__ pb,
    const float* __restrict__ ln1w, const float* __restrict__ ln1b,
    const float* __restrict__ l1w, const float* __restrict__ l1b,
    const float* __restrict__ ln2w, const float* __restrict__ ln2b,
    const float* __restrict__ l2w, const float* __restrict__ l2b,
    const float* __restrict__ ln3w, const float* __restrict__ ln3b,
    const float* __restrict__ l3w, const float* __restrict__ l3b,
    float* __restrict__ pos)
{
    int i = threadIdx.x;
    if (i >= 961) return;
    float b0 = (float)(i / 31) - 15.0f;
    float b1 = (float)(i % 31) - 15.0f;
    float p[11], t[11];
    #pragma unroll
    for (int j = 0; j < 11; j++) p[j] = b0 * pw[j] + b1 * pw[11 + j] + pb[j];
    lnrelu11(p, ln1w, ln1b);
    #pragma unroll
    for (int j = 0; j < 11; j++) {
        float s = l1b[j];
        #pragma unroll
        for (int k = 0; k < 11; k++) s = fmaf(p[k], l1w[k * 11 + j], s);
        t[j] = s;
    }
    lnrelu11(t, ln2w, ln2b);
    #pragma unroll
    for (int j = 0; j < 11; j++) {
        float s = l2b[j];
        #pragma unroll
        for (int k = 0; k < 11; k++) s = fmaf(t[k], l2w[k * 11 + j], s);
        p[j] = s;
    }
    lnrelu11(p, ln3w, ln3b);
    #pragma unroll
    for (int h = 0; h < 6; h++) {
        float s = l3b[h];
        #pragma unroll
        for (int k = 0; k < 11; k++) s = fmaf(p[k], l3w[k * 6 + h], s);
        pos[i * 6 + h] = s;
    }
}

// ---------------------------------------------------------------------------
// K0b: rpb[h][l][m] = mean_r pos[idx(l, key(m,r))][h]   (6,256,64)
// ---------------------------------------------------------------------------
__global__ __launch_bounds__(256) void k_rpb(const float* __restrict__ pos,
                                             float* __restrict__ rpb)
{
    int g = blockIdx.x * 256 + threadIdx.x;
    if (g >= 6 * 256 * 64) return;
    int h = g >> 14;
    int l = (g >> 6) & 255;
    int m = g & 63;
    int yl = l >> 4, xl = l & 15;
    int my = m >> 3, mx = m & 7;
    float s = 0.f;
    #pragma unroll
    for (int ry = 0; ry < 2; ry++) {
        #pragma unroll
        for (int rx = 0; rx < 2; rx++) {
            int y2 = my * 2 + ry, x2 = mx * 2 + rx;
            int idx = (yl - y2 + 15) * 31 + (xl - x2 + 15);
            s += pos[idx * 6 + h];
        }
    }
    rpb[g] = 0.25f * s;
}

// ---------------------------------------------------------------------------
// K1: conv1x1 180->36 + lrelu.  x NCHW fp32 -> h1 planar bf16 [b][36][sp]
// ---------------------------------------------------------------------------
__global__ __launch_bounds__(256) void k_conv1(const float* __restrict__ x,
                                               const float* __restrict__ w,
                                               const float* __restrict__ b,
                                               u16* __restrict__ h1)
{
    int pix = blockIdx.x * 256 + threadIdx.x;
    int bb = pix >> 16, sp = pix & 65535;
    float acc[36];
    #pragma unroll
    for (int j = 0; j < 36; j++) acc[j] = b[j];
    const float* xp = x + (size_t)bb * 180 * HW + sp;
    for (int c = 0; c < 180; c++) {
        float xv = xp[(size_t)c * HW];
        #pragma unroll
        for (int j = 0; j < 36; j++) acc[j] = fmaf(xv, w[c * 36 + j], acc[j]);
    }
    u16* hp = h1 + (size_t)bb * 36 * HW + sp;
    #pragma unroll
    for (int j = 0; j < 36; j++) {
        float v = acc[j];
        v = v >= 0.f ? v : 0.2f * v;
        hp[(size_t)j * HW] = f2bf(v);
    }
}

// ---------------------------------------------------------------------------
// K2: conv3x3 36->36 pad1 + lrelu.  h1 planar bf16 -> h2 planar bf16
// ---------------------------------------------------------------------------
__global__ __launch_bounds__(256) void k_conv3(const u16* __restrict__ h1,
                                               const float* __restrict__ w,
                                               const float* __restrict__ b,
                                               u16* __restrict__ h2)
{
    int tx = threadIdx.x, ty = threadIdx.y;
    int x0 = blockIdx.x * 16 + tx;
    int y0 = blockIdx.y * 16 + ty;
    int bb = blockIdx.z;
    float acc[36];
    #pragma unroll
    for (int j = 0; j < 36; j++) acc[j] = b[j];
    const u16* base = h1 + (size_t)bb * 36 * HW;
    for (int ky = 0; ky < 3; ky++) {
        int yy = y0 + ky - 1;
        if (yy < 0 || yy >= 256) continue;
        for (int kx = 0; kx < 3; kx++) {
            int xx = x0 + kx - 1;
            if (xx < 0 || xx >= 256) continue;
            const u16* ip = base + yy * 256 + xx;
            const float* wp = w + ((ky * 3 + kx) * 36) * 36;
            for (int c = 0; c < 36; c++) {
                float v = bf2f(ip[(size_t)c * HW]);
                #pragma unroll
                for (int j = 0; j < 36; j++) acc[j] = fmaf(v, wp[c * 36 + j], acc[j]);
            }
        }
    }
    u16* op = h2 + (size_t)bb * 36 * HW + y0 * 256 + x0;
    #pragma unroll
    for (int j = 0; j < 36; j++) {
        float v = acc[j];
        v = v >= 0.f ? v : 0.2f * v;
        op[(size_t)j * HW] = f2bf(v);
    }
}

// ---------------------------------------------------------------------------
// K3: qv = (conv1x1 36->180 (h2) + b3) * (conv1x1 180->180 (x) + lb)
//     OUTPUT: per-window transposed qvT[w][ch][l]  (ch 0..180, l 0..256)
// ---------------------------------------------------------------------------
__global__ __launch_bounds__(256) void k_gate(const u16* __restrict__ h2,
                                              const float* __restrict__ x,
                                              const float* __restrict__ w3,
                                              const float* __restrict__ b3,
                                              const float* __restrict__ lw,
                                              const float* __restrict__ lb,
                                              u16* __restrict__ qvT)
{
    int lane = threadIdx.x;
    int g = __builtin_amdgcn_readfirstlane((int)threadIdx.y);
    int cb = g * 45;
    int blk = blockIdx.x;
    int bb = blk >> 10;
    int r  = blk & 1023;
    int wx = r & 15;
    int yq = r >> 4;               // 0..63  (group of 4 image rows)
    int yl = lane >> 4, xl = lane & 15;
    int y  = yq * 4 + yl;
    int sp = y * 256 + wx * 16 + xl;
    int w  = bb * 256 + (yq >> 2) * 16 + wx;
    int l  = ((yq & 3) * 4 + yl) * 16 + xl;

    float ah[45], al[45];
    #pragma unroll
    for (int j = 0; j < 45; j++) { ah[j] = b3[cb + j]; al[j] = lb[cb + j]; }
    const u16* hp = h2 + (size_t)bb * 36 * HW + sp;
    for (int c = 0; c < 36; c++) {
        float hv = bf2f(hp[(size_t)c * HW]);
        #pragma unroll
        for (int j = 0; j < 45; j++) ah[j] = fmaf(hv, w3[c * 180 + cb + j], ah[j]);
    }
    const float* xp = x + (size_t)bb * 180 * HW + sp;
    for (int c = 0; c < 180; c++) {
        float xv = xp[(size_t)c * HW];
        #pragma unroll
        for (int j = 0; j < 45; j++) al[j] = fmaf(xv, lw[c * 180 + cb + j], al[j]);
    }
    u16* qp = qvT + (size_t)w * 180 * 256 + l;
    #pragma unroll
    for (int j = 0; j < 45; j++) qp[(size_t)(cb + j) * 256] = f2bf(ah[j] * al[j]);
}

// ---------------------------------------------------------------------------
// K4a: spatial attention per 16x16 window (reads qvT; writes yp slots 0..90)
//      Also zeroes yp slots 90..95 so k_proj can MFMA straight over [pix][192].
// ---------------------------------------------------------------------------
__global__ __launch_bounds__(256) void k_spat(const u16* __restrict__ qvT,
                                              const float* __restrict__ rpb,
                                              const float* __restrict__ slw,
                                              const float* __restrict__ slb,
                                              u16* __restrict__ yp)
{
    __shared__ __align__(16) float vp[6144];   // [6][64][16]
    int w = blockIdx.x;
    int bb = w >> 8, wy = (w >> 4) & 15, wx = w & 15;
    int t = threadIdx.x;
    int lane = t & 63, wv = t >> 6;
    const u16* qw = qvT + (size_t)w * 180 * 256;
    float s0 = slw[0], s1 = slw[1], s2 = slw[2], s3 = slw[3], sb = slb[0];
    // zero pad d=15
    for (int o = t; o < 384; o += 256) vp[(o >> 6) * 1024 + (o & 63) * 16 + 15] = 0.f;
    // vp staging: wave handles one (h,d) row (p = h*15+d), lane = m
    for (int it = 0; it < 23; it++) {
        int p = wv + it * 4;
        if (p < 90) {
            int mm = lane;
            int l0 = (mm >> 3) * 32 + (mm & 7) * 2;
            const u16* rp2 = qw + (size_t)(90 + p) * 256;
            float s = sb + s0 * bf2f(rp2[l0]) + s1 * bf2f(rp2[l0 + 1])
                         + s2 * bf2f(rp2[l0 + 16]) + s3 * bf2f(rp2[l0 + 17]);
            vp[(p / 15) * 1024 + mm * 16 + (p % 15)] = s;
        }
    }
    __syncthreads();
    int l = t;
    size_t pixl = (size_t)((bb * 256 + wy * 16 + (l >> 4)) * 256 + wx * 16 + (l & 15));
    u16* op = yp + pixl * 192;
    // zero pad slots 90..95 (uninitialized workspace could hold NaN patterns;
    // k_proj's MFMA K=192 multiplies them by zero weights, 0*NaN = NaN)
    ((u32*)op)[45] = 0u; ((u32*)op)[46] = 0u; ((u32*)op)[47] = 0u;
    for (int h = 0; h < 6; h++) {
        float q[16];
        #pragma unroll
        for (int d = 0; d < 15; d++) q[d] = bf2f(qw[(size_t)(h * 15 + d) * 256 + l]);
        q[15] = 0.f;
        float acc[16];
        #pragma unroll
        for (int d = 0; d < 16; d++) acc[d] = 0.f;
        const float* rp = rpb + ((h * 256 + l) << 6);
        const float4* vph = (const float4*)(vp + (h << 10));
        for (int m0 = 0; m0 < 64; m0 += 4) {
            float ra[4];
            *(float4*)ra = *(const float4*)(rp + m0);
            #pragma unroll
            for (int mm = 0; mm < 4; mm++) {
                int m = m0 + mm;
                float wvv[16];
                ((float4*)wvv)[0] = vph[m * 4 + 0];
                ((float4*)wvv)[1] = vph[m * 4 + 1];
                ((float4*)wvv)[2] = vph[m * 4 + 2];
                ((float4*)wvv)[3] = vph[m * 4 + 3];
                float s = 0.f;
                #pragma unroll
                for (int d2 = 0; d2 < 16; d2++) s = fmaf(q[d2], wvv[d2], s);
                s = s * (1.0f / 15.0f) + ra[mm];
                #pragma unroll
                for (int d2 = 0; d2 < 16; d2++) acc[d2] = fmaf(s, wvv[d2], acc[d2]);
            }
        }
        #pragma unroll
        for (int d = 0; d < 15; d++) op[h * 15 + d] = f2bf(acc[d]);
    }
}

// ---------------------------------------------------------------------------
// K4b: channel self-correlation per window — MFMA.
// ---------------------------------------------------------------------------
__global__ __launch_bounds__(256) void k_chan(const u16* __restrict__ qvT,
                                              u16* __restrict__ yp)
{
    __shared__ __align__(16) u16 cm[96 * 104];     // cmap bf16, stride 104
    __shared__ __align__(16) u16 xcb[128 * 104];   // xc half, stride 104
    int w = blockIdx.x;
    int bb = w >> 8, wy = (w >> 4) & 15, wx = w & 15;
    int t = threadIdx.x;
    int lane = t & 63, wv = t >> 6;
    int m = lane & 15, quad = lane >> 4;
    const u16* qw = qvT + (size_t)w * 180 * 256;

    // ---- phase 1: cmap ----
    int ct0 = (wv & 1) * 3, dt0 = (wv >> 1) * 3;
    f32x4 acc[3][3];
    #pragma unroll
    for (int i = 0; i < 3; i++)
        #pragma unroll
        for (int j = 0; j < 3; j++) {
            f32x4 z = {0.f, 0.f, 0.f, 0.f};
            acc[i][j] = z;
        }
    #pragma unroll
    for (int ks = 0; ks < 8; ks++) {
        bf16x8 A[3], B[3];
        #pragma unroll
        for (int i = 0; i < 3; i++)
            A[i] = *(const bf16x8*)(qw + (size_t)((ct0 + i) * 16 + m) * 256 + ks * 32 + quad * 8);
        #pragma unroll
        for (int j = 0; j < 3; j++) {
            int d = (dt0 + j) * 16 + m;
            int dd = d > 89 ? 89 : d;
            B[j] = *(const bf16x8*)(qw + (size_t)(90 + dd) * 256 + ks * 32 + quad * 8);
        }
        #pragma unroll
        for (int i = 0; i < 3; i++)
            #pragma unroll
            for (int j = 0; j < 3; j++)
                acc[i][j] = mfma16(A[i], B[j], acc[i][j]);
    }
    #pragma unroll
    for (int i = 0; i < 3; i++)
        #pragma unroll
        for (int j = 0; j < 3; j++)
            #pragma unroll
            for (int r = 0; r < 4; r++)
                cm[((ct0 + i) * 16 + quad * 4 + r) * 104 + (dt0 + j) * 16 + m] =
                    f2bf(acc[i][j][r] * (1.0f / 256.0f));
    __syncthreads();
    if (t < 96) {   // zero cmap columns 90..95 (pad garbage)
        u32* z = (u32*)(cm + t * 104 + 90);
        z[0] = 0; z[1] = 0; z[2] = 0;
    }
    __syncthreads();

    // ---- phase 2: xc, in two 128-row halves ----
    int base_pix = (bb * 256 + wy * 16) * 256 + wx * 16;
    const __bf16* qwb = (const __bf16*)qw;
    for (int half = 0; half < 2; half++) {
        #pragma unroll
        for (int i = 0; i < 2; i++) {
            int ltl = wv * 2 + i;           // 0..7
            int lt = half * 8 + ltl;
            bf16x8 A[3];
            #pragma unroll
            for (int ks = 0; ks < 3; ks++) {
                const __bf16* colp = qwb + lt * 16 + m;
                #pragma unroll
                for (int j2 = 0; j2 < 8; j2++) {
                    int d = ks * 32 + quad * 8 + j2;
                    int dd = d > 89 ? 89 : d;
                    A[ks][j2] = colp[(size_t)(90 + dd) * 256];
                }
            }
            for (int ct = 0; ct < 6; ct++) {
                f32x4 c4 = {0.f, 0.f, 0.f, 0.f};
                #pragma unroll
                for (int ks = 0; ks < 3; ks++) {
                    bf16x8 B = *(const bf16x8*)(cm + (ct * 16 + m) * 104 + ks * 32 + quad * 8);
                    c4 = mfma16(A[ks], B, c4);
                }
                #pragma unroll
                for (int r = 0; r < 4; r++)
                    xcb[(ltl * 16 + quad * 4 + r) * 104 + ct * 16 + m] = f2bf(c4[r]);
            }
        }
        __syncthreads();
        #pragma unroll
        for (int it = 0; it < 6; it++) {
            int gg = t + it * 256;          // < 1536
            int lrow = gg / 12, seg = gg % 12;
            int l = half * 128 + lrow;
            int pix = base_pix + (l >> 4) * 256 + (l & 15);
            *(uint4*)(yp + (size_t)pix * 192 + 96 + seg * 8) =
                *(const uint4*)(xcb + lrow * 104 + seg * 8);
        }
        __syncthreads();
    }
}

// ---------------------------------------------------------------------------
// K5a: weight prep for MFMA proj: pad proj_w (180x180) to [oc:192][k:192]
//      bf16 hi/lo split, transposed to A-fragment layout [oc][k].
//      K mapping mirrors yp slots: k 0..89 -> c 0..89, k 96..185 -> c 90..179,
//      k 90..95 / 186..191 -> zero.
// ---------------------------------------------------------------------------
__global__ __launch_bounds__(256) void k_wprep(const float* __restrict__ pjw,
                                               u16* __restrict__ whiT,
                                               u16* __restrict__ wloT)
{
    int g = blockIdx.x * 256 + threadIdx.x;    // < 36864 = 192*192
    int oc = g / 192, k = g % 192;
    int kp = -1;
    if (k < 90) kp = k;
    else if (k >= 96 && k < 186) kp = k - 6;
    float v = (kp >= 0 && oc < 180) ? pjw[kp * 180 + oc] : 0.f;
    u16 h = f2bf(v);
    float lo = v - bf2f(h);                    // exact (Sterbenz)
    whiT[g] = h;
    wloT[g] = f2bf(lo);
}

// ---------------------------------------------------------------------------
// K5: y = y_pre @ proj_w + proj_b ; RMSNorm ; + shortcut(x) ; write NCHW fp32
//     MFMA version: D[oc][pix] = sum_k W^T[oc][k] * T[pix][k], K=192 padded.
//     A = whiT/wloT (hi/lo bf16 split of fp32 weights -> fp32-level accuracy),
//     B = yp rows straight from global ([pix][192] bf16).
//     Block: 256 thr = 4 waves; 64 pixels/block; wave g owns oc 48g..48g+47.
//     D col = lane&15 = pixel -> 16-lane 64B contiguous x-loads/out-stores.
// ---------------------------------------------------------------------------
__global__ __launch_bounds__(256) void k_proj(const u16* __restrict__ yp,
                                              const float* __restrict__ x,
                                              const u16* __restrict__ whiT,
                                              const u16* __restrict__ wloT,
                                              const float* __restrict__ pb,
                                              const float* __restrict__ nw,
                                              float* __restrict__ out)
{
    __shared__ float part[4][4][16];
    int t = threadIdx.x;
    int lane = t & 63;
    int g = __builtin_amdgcn_readfirstlane(t >> 6);
    int m = lane & 15, q = lane >> 4;
    int pix0 = blockIdx.x * 64;
    int ocbase = g * 48;

    f32x4 acc[3][4];
    #pragma unroll
    for (int mt = 0; mt < 3; mt++)
        #pragma unroll
        for (int pt = 0; pt < 4; pt++) {
            f32x4 z = {0.f, 0.f, 0.f, 0.f};
            acc[mt][pt] = z;
        }

    const u16* bbase = yp + (size_t)pix0 * 192;
    #pragma unroll 2
    for (int ks = 0; ks < 6; ks++) {
        bf16x8 B[4];
        #pragma unroll
        for (int pt = 0; pt < 4; pt++)
            B[pt] = *(const bf16x8*)(bbase + (size_t)(pt * 16 + m) * 192 + ks * 32 + q * 8);
        #pragma unroll
        for (int mt = 0; mt < 3; mt++) {
            bf16x8 Ah = *(const bf16x8*)(whiT + (size_t)(ocbase + mt * 16 + m) * 192 + ks * 32 + q * 8);
            bf16x8 Al = *(const bf16x8*)(wloT + (size_t)(ocbase + mt * 16 + m) * 192 + ks * 32 + q * 8);
            #pragma unroll
            for (int pt = 0; pt < 4; pt++) {
                acc[mt][pt] = mfma16(Ah, B[pt], acc[mt][pt]);
                acc[mt][pt] = mfma16(Al, B[pt], acc[mt][pt]);
            }
        }
    }

    // ---- epilogue: bias, per-pixel RMS, shortcut add, NCHW store ----
    float pbv[3][4], nwv[3][4];
    #pragma unroll
    for (int mt = 0; mt < 3; mt++)
        #pragma unroll
        for (int r = 0; r < 4; r++) {
            int oc = ocbase + mt * 16 + q * 4 + r;
            bool ok = oc < 180;
            pbv[mt][r] = ok ? pb[oc] : 0.f;
            nwv[mt][r] = ok ? nw[oc] : 0.f;
        }
    float ss[4] = {0.f, 0.f, 0.f, 0.f};
    #pragma unroll
    for (int mt = 0; mt < 3; mt++)
        #pragma unroll
        for (int pt = 0; pt < 4; pt++)
            #pragma unroll
            for (int r = 0; r < 4; r++) {
                float y = acc[mt][pt][r] + pbv[mt][r];
                acc[mt][pt][r] = y;
                ss[pt] = fmaf(y, y, ss[pt]);
            }
    #pragma unroll
    for (int pt = 0; pt < 4; pt++) {
        ss[pt] += __shfl_xor(ss[pt], 16);
        ss[pt] += __shfl_xor(ss[pt], 32);
    }
    if (q == 0) {
        #pragma unroll
        for (int pt = 0; pt < 4; pt++) part[g][pt][m] = ss[pt];
    }
    __syncthreads();
    float scale[4];
    #pragma unroll
    for (int pt = 0; pt < 4; pt++) {
        float tot = part[0][pt][m] + part[1][pt][m] + part[2][pt][m] + part[3][pt][m];
        scale[pt] = 1.0f / sqrtf(tot * (1.0f / 180.0f) + 1.1920929e-7f);
    }

    int bb = pix0 >> 16, sp0 = pix0 & 65535;
    const float* xb = x + (size_t)bb * 180 * HW + sp0 + m;
    float* ob = out + (size_t)bb * 180 * HW + sp0 + m;
    #pragma unroll
    for (int mt = 0; mt < 3; mt++)
        #pragma unroll
        for (int r = 0; r < 4; r++) {
            int oc = ocbase + mt * 16 + q * 4 + r;
            if (oc < 180) {
                #pragma unroll
                for (int pt = 0; pt < 4; pt++) {
                    size_t off = (size_t)oc * HW + pt * 16;
                    ob[off] = xb[off] + acc[mt][pt][r] * scale[pt] * nwv[mt][r];
                }
            }
        }
}

// ---------------------------------------------------------------------------
extern "C" void kernel_launch(void* const* d_in, const int* in_sizes, int n_in,
                              void* d_out, int out_size, void* d_ws, size_t ws_size,
                              hipStream_t stream)
{
    const float* x    = (const float*)d_in[0];
    const float* w1   = (const float*)d_in[1];
    const float* b1   = (const float*)d_in[2];
    const float* w2   = (const float*)d_in[3];
    const float* b2   = (const float*)d_in[4];
    const float* w3   = (const float*)d_in[5];
    const float* b3   = (const float*)d_in[6];
    const float* lw   = (const float*)d_in[7];
    const float* lb   = (const float*)d_in[8];
    const float* slw  = (const float*)d_in[9];
    const float* slb  = (const float*)d_in[10];
    const float* pw   = (const float*)d_in[11];
    const float* pb   = (const float*)d_in[12];
    const float* ln1w = (const float*)d_in[13];
    const float* ln1b = (const float*)d_in[14];
    const float* l1w  = (const float*)d_in[15];
    const float* l1b  = (const float*)d_in[16];
    const float* ln2w = (const float*)d_in[17];
    const float* ln2b = (const float*)d_in[18];
    const float* l2w  = (const float*)d_in[19];
    const float* l2b  = (const float*)d_in[20];
    const float* ln3w = (const float*)d_in[21];
    const float* ln3b = (const float*)d_in[22];
    const float* l3w  = (const float*)d_in[23];
    const float* l3b  = (const float*)d_in[24];
    const float* pjw  = (const float*)d_in[25];
    const float* pjb  = (const float*)d_in[26];
    const float* nw   = (const float*)d_in[27];
    float* out = (float*)d_out;

    char* ws = (char*)d_ws;
    // layout (time-disjoint overlap: qvT reuses dead h1 region; whiT/wloT
    // reuse dead h2 region after k_gate)
    float* pos = (float*)(ws + 0);            // 23 KB
    float* rpb = (float*)(ws + 24576);        // 384 KB  -> end 417792
    u16*  h2  = (u16*)(ws + 417792);          // 18.87 MB -> end 19292160
    u16*  whiT = (u16*)(ws + 417792);         // 72 KB (written AFTER k_gate)
    u16*  wloT = (u16*)(ws + 417792 + 73728); // 72 KB
    u16*  h1  = (u16*)(ws + 19292160);        // 18.87 MB -> end 38166528 (dead after conv3)
    u16*  qvT = (u16*)(ws + 19292160);        // 94.37 MB -> end 113664000 (written in k_gate)
    u16*  yp  = (u16*)(ws + 113664000);       // 100.66 MB -> end 214327296
    // total ws use: ~214.3 MB

    k_pos<<<dim3(1), dim3(1024), 0, stream>>>(pw, pb, ln1w, ln1b, l1w, l1b,
                                              ln2w, ln2b, l2w, l2b, ln3w, ln3b,
                                              l3w, l3b, pos);
    k_rpb<<<dim3(384), dim3(256), 0, stream>>>(pos, rpb);
    k_conv1<<<dim3(1024), dim3(256), 0, stream>>>(x, w1, b1, h1);
    k_conv3<<<dim3(16, 16, 4), dim3(16, 16), 0, stream>>>(h1, w2, b2, h2);
    k_gate<<<dim3(4096), dim3(64, 4), 0, stream>>>(h2, x, w3, b3, lw, lb, qvT);
    k_wprep<<<dim3(144), dim3(256), 0, stream>>>(pjw, whiT, wloT);   // h2 dead now
    k_spat<<<dim3(1024), dim3(256), 0, stream>>>(qvT, rpb, slw, slb, yp);
    k_chan<<<dim3(1024), dim3(256), 0, stream>>>(qvT, yp);
    k_proj<<<dim3(4096), dim3(256), 0, stream>>>(yp, x, whiT, wloT, pjb, nw, out);
}

// Round 2
// 1088.518 us; speedup vs baseline: 1.4049x; 1.1769x over previous
//
#include <hip/hip_runtime.h>
#include <stdint.h>

typedef unsigned short u16;
typedef unsigned int   u32;

#define HW 65536   // 256*256

typedef __bf16 bf16x8 __attribute__((ext_vector_type(8)));
typedef float  f32x4  __attribute__((ext_vector_type(4)));

static __device__ __forceinline__ float bf2f(u16 h) {
    u32 u = ((u32)h) << 16;
    return __builtin_bit_cast(float, u);
}
static __device__ __forceinline__ u16 f2bf(float f) {
    u32 u = __builtin_bit_cast(u32, f);
    u += 0x7fffu + ((u >> 16) & 1u);   // RNE
    return (u16)(u >> 16);
}
static __device__ __forceinline__ void bf2x2(u32 u, float& a, float& b) {
    a = __builtin_bit_cast(float, u << 16);
    b = __builtin_bit_cast(float, u & 0xffff0000u);
}
static __device__ __forceinline__ f32x4 mfma16(bf16x8 a, bf16x8 b, f32x4 c) {
    return __builtin_amdgcn_mfma_f32_16x16x32_bf16(a, b, c, 0, 0, 0);
}

// ---------------------------------------------------------------------------
// K0a: relative position bias MLP: (961,2) -> (961,6)
// ---------------------------------------------------------------------------
static __device__ __forceinline__ void lnrelu11(float* p, const float* __restrict__ w,
                                                const float* __restrict__ b) {
    float m = 0.f;
    #pragma unroll
    for (int k = 0; k < 11; k++) m += p[k];
    m *= (1.0f / 11.0f);
    float v = 0.f;
    #pragma unroll
    for (int k = 0; k < 11; k++) { float d = p[k] - m; v = fmaf(d, d, v); }
    v *= (1.0f / 11.0f);
    float r = 1.0f / sqrtf(v + 1e-5f);
    #pragma unroll
    for (int k = 0; k < 11; k++) {
        float t = (p[k] - m) * r * w[k] + b[k];
        p[k] = t > 0.f ? t : 0.f;
    }
}

__global__ __launch_bounds__(1024) void k_pos(
    const float* __restrict__ pw, const float* __restrict__ pb,
    const float* __restrict__ ln1w, const float* __restrict__ ln1b,
    const float* __restrict__ l1w, const float* __restrict__ l1b,
    const float* __restrict__ ln2w, const float* __restrict__ ln2b,
    const float* __restrict__ l2w, const float* __restrict__ l2b,
    const float* __restrict__ ln3w, const float* __restrict__ ln3b,
    const float* __restrict__ l3w, const float* __restrict__ l3b,
    float* __restrict__ pos)
{
    int i = threadIdx.x;
    if (i >= 961) return;
    float b0 = (float)(i / 31) - 15.0f;
    float b1 = (float)(i % 31) - 15.0f;
    float p[11], t[11];
    #pragma unroll
    for (int j = 0; j < 11; j++) p[j] = b0 * pw[j] + b1 * pw[11 + j] + pb[j];
    lnrelu11(p, ln1w, ln1b);
    #pragma unroll
    for (int j = 0; j < 11; j++) {
        float s = l1b[j];
        #pragma unroll
        for (int k = 0; k < 11; k++) s = fmaf(p[k], l1w[k * 11 + j], s);
        t[j] = s;
    }
    lnrelu11(t, ln2w, ln2b);
    #pragma unroll
    for (int j = 0; j < 11; j++) {
        float s = l2b[j];
        #pragma unroll
        for (int k = 0; k < 11; k++) s = fmaf(t[k], l2w[k * 11 + j], s);
        p[j] = s;
    }
    lnrelu11(p, ln3w, ln3b);
    #pragma unroll
    for (int h = 0; h < 6; h++) {
        float s = l3b[h];
        #pragma unroll
        for (int k = 0; k < 11; k++) s = fmaf(p[k], l3w[k * 6 + h], s);
        pos[i * 6 + h] = s;
    }
}

// ---------------------------------------------------------------------------
// K0b: rpb[h][l][m] = mean_r pos[idx(l, key(m,r))][h]   (6,256,64)
// ---------------------------------------------------------------------------
__global__ __launch_bounds__(256) void k_rpb(const float* __restrict__ pos,
                                             float* __restrict__ rpb)
{
    int g = blockIdx.x * 256 + threadIdx.x;
    if (g >= 6 * 256 * 64) return;
    int h = g >> 14;
    int l = (g >> 6) & 255;
    int m = g & 63;
    int yl = l >> 4, xl = l & 15;
    int my = m >> 3, mx = m & 7;
    float s = 0.f;
    #pragma unroll
    for (int ry = 0; ry < 2; ry++) {
        #pragma unroll
        for (int rx = 0; rx < 2; rx++) {
            int y2 = my * 2 + ry, x2 = mx * 2 + rx;
            int idx = (yl - y2 + 15) * 31 + (xl - x2 + 15);
            s += pos[idx * 6 + h];
        }
    }
    rpb[g] = 0.25f * s;
}

// ---------------------------------------------------------------------------
// K1: conv1x1 180->36 + lrelu.  x NCHW fp32 -> h1 planar bf16 [b][36][sp]
// ---------------------------------------------------------------------------
__global__ __launch_bounds__(256) void k_conv1(const float* __restrict__ x,
                                               const float* __restrict__ w,
                                               const float* __restrict__ b,
                                               u16* __restrict__ h1)
{
    int pix = blockIdx.x * 256 + threadIdx.x;
    int bb = pix >> 16, sp = pix & 65535;
    float acc[36];
    #pragma unroll
    for (int j = 0; j < 36; j++) acc[j] = b[j];
    const float* xp = x + (size_t)bb * 180 * HW + sp;
    for (int c = 0; c < 180; c++) {
        float xv = xp[(size_t)c * HW];
        #pragma unroll
        for (int j = 0; j < 36; j++) acc[j] = fmaf(xv, w[c * 36 + j], acc[j]);
    }
    u16* hp = h1 + (size_t)bb * 36 * HW + sp;
    #pragma unroll
    for (int j = 0; j < 36; j++) {
        float v = acc[j];
        v = v >= 0.f ? v : 0.2f * v;
        hp[(size_t)j * HW] = f2bf(v);
    }
}

// ---------------------------------------------------------------------------
// K2: conv3x3 36->36 pad1 + lrelu.  h1 planar bf16 -> h2 planar bf16
// ---------------------------------------------------------------------------
__global__ __launch_bounds__(256) void k_conv3(const u16* __restrict__ h1,
                                               const float* __restrict__ w,
                                               const float* __restrict__ b,
                                               u16* __restrict__ h2)
{
    int tx = threadIdx.x, ty = threadIdx.y;
    int x0 = blockIdx.x * 16 + tx;
    int y0 = blockIdx.y * 16 + ty;
    int bb = blockIdx.z;
    float acc[36];
    #pragma unroll
    for (int j = 0; j < 36; j++) acc[j] = b[j];
    const u16* base = h1 + (size_t)bb * 36 * HW;
    for (int ky = 0; ky < 3; ky++) {
        int yy = y0 + ky - 1;
        if (yy < 0 || yy >= 256) continue;
        for (int kx = 0; kx < 3; kx++) {
            int xx = x0 + kx - 1;
            if (xx < 0 || xx >= 256) continue;
            const u16* ip = base + yy * 256 + xx;
            const float* wp = w + ((ky * 3 + kx) * 36) * 36;
            for (int c = 0; c < 36; c++) {
                float v = bf2f(ip[(size_t)c * HW]);
                #pragma unroll
                for (int j = 0; j < 36; j++) acc[j] = fmaf(v, wp[c * 36 + j], acc[j]);
            }
        }
    }
    u16* op = h2 + (size_t)bb * 36 * HW + y0 * 256 + x0;
    #pragma unroll
    for (int j = 0; j < 36; j++) {
        float v = acc[j];
        v = v >= 0.f ? v : 0.2f * v;
        op[(size_t)j * HW] = f2bf(v);
    }
}

// ---------------------------------------------------------------------------
// K3a: weight prep for MFMA gate:
//   gating lw (180x180, [in][out]) -> gwh/gwl [oc:192][k:192] bf16 hi/lo
//   conv   w3 (36x180,  [in][out]) -> cwh/cwl [oc:192][k:64]  bf16 hi/lo
// ---------------------------------------------------------------------------
__global__ __launch_bounds__(256) void k_wgprep(const float* __restrict__ lw,
                                                const float* __restrict__ w3,
                                                u16* __restrict__ gwh,
                                                u16* __restrict__ gwl,
                                                u16* __restrict__ cwh,
                                                u16* __restrict__ cwl)
{
    int gidx = blockIdx.x * 256 + threadIdx.x;   // < 49152
    if (gidx < 36864) {
        int oc = gidx / 192, k = gidx % 192;
        float v = (oc < 180 && k < 180) ? lw[k * 180 + oc] : 0.f;
        u16 h = f2bf(v);
        float lo = v - bf2f(h);
        gwh[gidx] = h;
        gwl[gidx] = f2bf(lo);
    } else {
        int r = gidx - 36864;                    // < 12288
        int oc = r / 64, k = r % 64;
        float v = (oc < 180 && k < 36) ? w3[k * 180 + oc] : 0.f;
        u16 h = f2bf(v);
        float lo = v - bf2f(h);
        cwh[r] = h;
        cwl[r] = f2bf(lo);
    }
}

// ---------------------------------------------------------------------------
// K3: qv = (conv1x1 36->180 (h2) + b3) * (conv1x1 180->180 (x) + lb)
//     MFMA version.  OUTPUT: per-window transposed qvT[w][ch][l].
//     Block = quarter window (64 pixels = 4 rows); 4 waves x 48 oc each.
//     A = prepped weights [oc][k] hi/lo; B = x (fp32 -> bf16 hi/lo split,
//     3 MFMAs: xh*wh + xh*wl + xl*wh) and h2 (exact bf16, 2 MFMAs: wh+wl).
//     D col = lane&15 = pixel -> 16-lane 64B coalesced x loads.
// ---------------------------------------------------------------------------
__global__ __launch_bounds__(256) void k_gate(const u16* __restrict__ h2,
                                              const float* __restrict__ x,
                                              const u16* __restrict__ gwh,
                                              const u16* __restrict__ gwl,
                                              const u16* __restrict__ cwh,
                                              const u16* __restrict__ cwl,
                                              const float* __restrict__ b3,
                                              const float* __restrict__ lb,
                                              u16* __restrict__ qvT)
{
    int t = threadIdx.x;
    int lane = t & 63;
    int g = __builtin_amdgcn_readfirstlane(t >> 6);
    int m = lane & 15, q = lane >> 4;
    int blk = blockIdx.x;
    int w  = blk >> 2;                 // window index
    int lq = blk & 3;                  // quarter (4 rows) within window
    int bb = w >> 8, wy = (w >> 4) & 15, wx = w & 15;
    int ocb = g * 48;
    int sp0 = (wy * 16 + lq * 4) * 256 + wx * 16 + m;   // + pt*256 per pix-tile
    const float* xb = x + (size_t)bb * 180 * HW;
    const u16*  hb = h2 + (size_t)bb * 36 * HW;

    f32x4 accG[3][4], accC[3][4];
    #pragma unroll
    for (int mt = 0; mt < 3; mt++)
        #pragma unroll
        for (int pt = 0; pt < 4; pt++) {
            f32x4 z = {0.f, 0.f, 0.f, 0.f};
            accG[mt][pt] = z;
            accC[mt][pt] = z;
        }

    // ---- gating path: K = 192 (180 real) ----
    #pragma unroll 2
    for (int ks = 0; ks < 6; ks++) {
        float xv[4][8];
        #pragma unroll
        for (int pt = 0; pt < 4; pt++)
            #pragma unroll
            for (int j = 0; j < 8; j++) {
                int c = ks * 32 + q * 8 + j;
                if (c > 179) c = 179;          // pad rows have zero weights
                xv[pt][j] = xb[(size_t)c * HW + sp0 + pt * 256];
            }
        bf16x8 Bh[4], Bl[4];
        #pragma unroll
        for (int pt = 0; pt < 4; pt++)
            #pragma unroll
            for (int j = 0; j < 8; j++) {
                float v = xv[pt][j];
                __bf16 hi = (__bf16)v;
                Bh[pt][j] = hi;
                Bl[pt][j] = (__bf16)(v - (float)hi);
            }
        #pragma unroll
        for (int mt = 0; mt < 3; mt++) {
            bf16x8 Ah = *(const bf16x8*)(gwh + (size_t)(ocb + mt * 16 + m) * 192 + ks * 32 + q * 8);
            bf16x8 Al = *(const bf16x8*)(gwl + (size_t)(ocb + mt * 16 + m) * 192 + ks * 32 + q * 8);
            #pragma unroll
            for (int pt = 0; pt < 4; pt++) {
                accG[mt][pt] = mfma16(Ah, Bh[pt], accG[mt][pt]);
                accG[mt][pt] = mfma16(Al, Bh[pt], accG[mt][pt]);
                accG[mt][pt] = mfma16(Ah, Bl[pt], accG[mt][pt]);
            }
        }
    }

    // ---- conv path: K = 64 (36 real), h2 already exact bf16 ----
    #pragma unroll
    for (int ks = 0; ks < 2; ks++) {
        bf16x8 B[4];
        #pragma unroll
        for (int pt = 0; pt < 4; pt++)
            #pragma unroll
            for (int j = 0; j < 8; j++) {
                int c = ks * 32 + q * 8 + j;
                if (c > 35) c = 35;            // pad rows have zero weights
                B[pt][j] = __builtin_bit_cast(__bf16, hb[(size_t)c * HW + sp0 + pt * 256]);
            }
        #pragma unroll
        for (int mt = 0; mt < 3; mt++) {
            bf16x8 Ah = *(const bf16x8*)(cwh + (size_t)(ocb + mt * 16 + m) * 64 + ks * 32 + q * 8);
            bf16x8 Al = *(const bf16x8*)(cwl + (size_t)(ocb + mt * 16 + m) * 64 + ks * 32 + q * 8);
            #pragma unroll
            for (int pt = 0; pt < 4; pt++) {
                accC[mt][pt] = mfma16(Ah, B[pt], accC[mt][pt]);
                accC[mt][pt] = mfma16(Al, B[pt], accC[mt][pt]);
            }
        }
    }

    // ---- epilogue: bias, gate multiply, bf16 store to qvT[w][oc][l] ----
    u16* qw = qvT + (size_t)w * 180 * 256 + lq * 64 + m;
    #pragma unroll
    for (int mt = 0; mt < 3; mt++)
        #pragma unroll
        for (int r = 0; r < 4; r++) {
            int oc = ocb + mt * 16 + q * 4 + r;
            if (oc < 180) {
                float bc = b3[oc], bg = lb[oc];
                #pragma unroll
                for (int pt = 0; pt < 4; pt++) {
                    float ah = accC[mt][pt][r] + bc;
                    float al = accG[mt][pt][r] + bg;
                    qw[(size_t)oc * 256 + pt * 16] = f2bf(ah * al);
                }
            }
        }
}

// ---------------------------------------------------------------------------
// K4a: spatial attention per 16x16 window (reads qvT; writes yp slots 0..90)
//      Also zeroes yp slots 90..95 so k_proj can MFMA straight over [pix][192].
// ---------------------------------------------------------------------------
__global__ __launch_bounds__(256) void k_spat(const u16* __restrict__ qvT,
                                              const float* __restrict__ rpb,
                                              const float* __restrict__ slw,
                                              const float* __restrict__ slb,
                                              u16* __restrict__ yp)
{
    __shared__ __align__(16) float vp[6144];   // [6][64][16]
    int w = blockIdx.x;
    int bb = w >> 8, wy = (w >> 4) & 15, wx = w & 15;
    int t = threadIdx.x;
    int lane = t & 63, wv = t >> 6;
    const u16* qw = qvT + (size_t)w * 180 * 256;
    float s0 = slw[0], s1 = slw[1], s2 = slw[2], s3 = slw[3], sb = slb[0];
    // zero pad d=15
    for (int o = t; o < 384; o += 256) vp[(o >> 6) * 1024 + (o & 63) * 16 + 15] = 0.f;
    // vp staging: wave handles one (h,d) row (p = h*15+d), lane = m
    for (int it = 0; it < 23; it++) {
        int p = wv + it * 4;
        if (p < 90) {
            int mm = lane;
            int l0 = (mm >> 3) * 32 + (mm & 7) * 2;
            const u16* rp2 = qw + (size_t)(90 + p) * 256;
            float s = sb + s0 * bf2f(rp2[l0]) + s1 * bf2f(rp2[l0 + 1])
                         + s2 * bf2f(rp2[l0 + 16]) + s3 * bf2f(rp2[l0 + 17]);
            vp[(p / 15) * 1024 + mm * 16 + (p % 15)] = s;
        }
    }
    __syncthreads();
    int l = t;
    size_t pixl = (size_t)((bb * 256 + wy * 16 + (l >> 4)) * 256 + wx * 16 + (l & 15));
    u16* op = yp + pixl * 192;
    // zero pad slots 90..95 (uninitialized workspace could hold NaN patterns;
    // k_proj's MFMA K=192 multiplies them by zero weights, 0*NaN = NaN)
    ((u32*)op)[45] = 0u; ((u32*)op)[46] = 0u; ((u32*)op)[47] = 0u;
    for (int h = 0; h < 6; h++) {
        float q[16];
        #pragma unroll
        for (int d = 0; d < 15; d++) q[d] = bf2f(qw[(size_t)(h * 15 + d) * 256 + l]);
        q[15] = 0.f;
        float acc[16];
        #pragma unroll
        for (int d = 0; d < 16; d++) acc[d] = 0.f;
        const float* rp = rpb + ((h * 256 + l) << 6);
        const float4* vph = (const float4*)(vp + (h << 10));
        for (int m0 = 0; m0 < 64; m0 += 4) {
            float ra[4];
            *(float4*)ra = *(const float4*)(rp + m0);
            #pragma unroll
            for (int mm = 0; mm < 4; mm++) {
                int m = m0 + mm;
                float wvv[16];
                ((float4*)wvv)[0] = vph[m * 4 + 0];
                ((float4*)wvv)[1] = vph[m * 4 + 1];
                ((float4*)wvv)[2] = vph[m * 4 + 2];
                ((float4*)wvv)[3] = vph[m * 4 + 3];
                float s = 0.f;
                #pragma unroll
                for (int d2 = 0; d2 < 16; d2++) s = fmaf(q[d2], wvv[d2], s);
                s = s * (1.0f / 15.0f) + ra[mm];
                #pragma unroll
                for (int d2 = 0; d2 < 16; d2++) acc[d2] = fmaf(s, wvv[d2], acc[d2]);
            }
        }
        #pragma unroll
        for (int d = 0; d < 15; d++) op[h * 15 + d] = f2bf(acc[d]);
    }
}

// ---------------------------------------------------------------------------
// K4b: channel self-correlation per window — MFMA.
// ---------------------------------------------------------------------------
__global__ __launch_bounds__(256) void k_chan(const u16* __restrict__ qvT,
                                              u16* __restrict__ yp)
{
    __shared__ __align__(16) u16 cm[96 * 104];     // cmap bf16, stride 104
    __shared__ __align__(16) u16 xcb[128 * 104];   // xc half, stride 104
    int w = blockIdx.x;
    int bb = w >> 8, wy = (w >> 4) & 15, wx = w & 15;
    int t = threadIdx.x;
    int lane = t & 63, wv = t >> 6;
    int m = lane & 15, quad = lane >> 4;
    const u16* qw = qvT + (size_t)w * 180 * 256;

    // ---- phase 1: cmap ----
    int ct0 = (wv & 1) * 3, dt0 = (wv >> 1) * 3;
    f32x4 acc[3][3];
    #pragma unroll
    for (int i = 0; i < 3; i++)
        #pragma unroll
        for (int j = 0; j < 3; j++) {
            f32x4 z = {0.f, 0.f, 0.f, 0.f};
            acc[i][j] = z;
        }
    #pragma unroll
    for (int ks = 0; ks < 8; ks++) {
        bf16x8 A[3], B[3];
        #pragma unroll
        for (int i = 0; i < 3; i++)
            A[i] = *(const bf16x8*)(qw + (size_t)((ct0 + i) * 16 + m) * 256 + ks * 32 + quad * 8);
        #pragma unroll
        for (int j = 0; j < 3; j++) {
            int d = (dt0 + j) * 16 + m;
            int dd = d > 89 ? 89 : d;
            B[j] = *(const bf16x8*)(qw + (size_t)(90 + dd) * 256 + ks * 32 + quad * 8);
        }
        #pragma unroll
        for (int i = 0; i < 3; i++)
            #pragma unroll
            for (int j = 0; j < 3; j++)
                acc[i][j] = mfma16(A[i], B[j], acc[i][j]);
    }
    #pragma unroll
    for (int i = 0; i < 3; i++)
        #pragma unroll
        for (int j = 0; j < 3; j++)
            #pragma unroll
            for (int r = 0; r < 4; r++)
                cm[((ct0 + i) * 16 + quad * 4 + r) * 104 + (dt0 + j) * 16 + m] =
                    f2bf(acc[i][j][r] * (1.0f / 256.0f));
    __syncthreads();
    if (t < 96) {   // zero cmap columns 90..95 (pad garbage)
        u32* z = (u32*)(cm + t * 104 + 90);
        z[0] = 0; z[1] = 0; z[2] = 0;
    }
    __syncthreads();

    // ---- phase 2: xc, in two 128-row halves ----
    int base_pix = (bb * 256 + wy * 16) * 256 + wx * 16;
    const __bf16* qwb = (const __bf16*)qw;
    for (int half = 0; half < 2; half++) {
        #pragma unroll
        for (int i = 0; i < 2; i++) {
            int ltl = wv * 2 + i;           // 0..7
            int lt = half * 8 + ltl;
            bf16x8 A[3];
            #pragma unroll
            for (int ks = 0; ks < 3; ks++) {
                const __bf16* colp = qwb + lt * 16 + m;
                #pragma unroll
                for (int j2 = 0; j2 < 8; j2++) {
                    int d = ks * 32 + quad * 8 + j2;
                    int dd = d > 89 ? 89 : d;
                    A[ks][j2] = colp[(size_t)(90 + dd) * 256];
                }
            }
            for (int ct = 0; ct < 6; ct++) {
                f32x4 c4 = {0.f, 0.f, 0.f, 0.f};
                #pragma unroll
                for (int ks = 0; ks < 3; ks++) {
                    bf16x8 B = *(const bf16x8*)(cm + (ct * 16 + m) * 104 + ks * 32 + quad * 8);
                    c4 = mfma16(A[ks], B, c4);
                }
                #pragma unroll
                for (int r = 0; r < 4; r++)
                    xcb[(ltl * 16 + quad * 4 + r) * 104 + ct * 16 + m] = f2bf(c4[r]);
            }
        }
        __syncthreads();
        #pragma unroll
        for (int it = 0; it < 6; it++) {
            int gg = t + it * 256;          // < 1536
            int lrow = gg / 12, seg = gg % 12;
            int l = half * 128 + lrow;
            int pix = base_pix + (l >> 4) * 256 + (l & 15);
            *(uint4*)(yp + (size_t)pix * 192 + 96 + seg * 8) =
                *(const uint4*)(xcb + lrow * 104 + seg * 8);
        }
        __syncthreads();
    }
}

// ---------------------------------------------------------------------------
// K5a: weight prep for MFMA proj: pad proj_w (180x180) to [oc:192][k:192]
//      bf16 hi/lo split, transposed to A-fragment layout [oc][k].
//      K mapping mirrors yp slots: k 0..89 -> c 0..89, k 96..185 -> c 90..179,
//      k 90..95 / 186..191 -> zero.
// ---------------------------------------------------------------------------
__global__ __launch_bounds__(256) void k_wprep(const float* __restrict__ pjw,
                                               u16* __restrict__ whiT,
                                               u16* __restrict__ wloT)
{
    int g = blockIdx.x * 256 + threadIdx.x;    // < 36864 = 192*192
    int oc = g / 192, k = g % 192;
    int kp = -1;
    if (k < 90) kp = k;
    else if (k >= 96 && k < 186) kp = k - 6;
    float v = (kp >= 0 && oc < 180) ? pjw[kp * 180 + oc] : 0.f;
    u16 h = f2bf(v);
    float lo = v - bf2f(h);                    // exact (Sterbenz)
    whiT[g] = h;
    wloT[g] = f2bf(lo);
}

// ---------------------------------------------------------------------------
// K5: y = y_pre @ proj_w + proj_b ; RMSNorm ; + shortcut(x) ; write NCHW fp32
//     MFMA version: D[oc][pix] = sum_k W^T[oc][k] * T[pix][k], K=192 padded.
// ---------------------------------------------------------------------------
__global__ __launch_bounds__(256) void k_proj(const u16* __restrict__ yp,
                                              const float* __restrict__ x,
                                              const u16* __restrict__ whiT,
                                              const u16* __restrict__ wloT,
                                              const float* __restrict__ pb,
                                              const float* __restrict__ nw,
                                              float* __restrict__ out)
{
    __shared__ float part[4][4][16];
    int t = threadIdx.x;
    int lane = t & 63;
    int g = __builtin_amdgcn_readfirstlane(t >> 6);
    int m = lane & 15, q = lane >> 4;
    int pix0 = blockIdx.x * 64;
    int ocbase = g * 48;

    f32x4 acc[3][4];
    #pragma unroll
    for (int mt = 0; mt < 3; mt++)
        #pragma unroll
        for (int pt = 0; pt < 4; pt++) {
            f32x4 z = {0.f, 0.f, 0.f, 0.f};
            acc[mt][pt] = z;
        }

    const u16* bbase = yp + (size_t)pix0 * 192;
    #pragma unroll 2
    for (int ks = 0; ks < 6; ks++) {
        bf16x8 B[4];
        #pragma unroll
        for (int pt = 0; pt < 4; pt++)
            B[pt] = *(const bf16x8*)(bbase + (size_t)(pt * 16 + m) * 192 + ks * 32 + q * 8);
        #pragma unroll
        for (int mt = 0; mt < 3; mt++) {
            bf16x8 Ah = *(const bf16x8*)(whiT + (size_t)(ocbase + mt * 16 + m) * 192 + ks * 32 + q * 8);
            bf16x8 Al = *(const bf16x8*)(wloT + (size_t)(ocbase + mt * 16 + m) * 192 + ks * 32 + q * 8);
            #pragma unroll
            for (int pt = 0; pt < 4; pt++) {
                acc[mt][pt] = mfma16(Ah, B[pt], acc[mt][pt]);
                acc[mt][pt] = mfma16(Al, B[pt], acc[mt][pt]);
            }
        }
    }

    // ---- epilogue: bias, per-pixel RMS, shortcut add, NCHW store ----
    float pbv[3][4], nwv[3][4];
    #pragma unroll
    for (int mt = 0; mt < 3; mt++)
        #pragma unroll
        for (int r = 0; r < 4; r++) {
            int oc = ocbase + mt * 16 + q * 4 + r;
            bool ok = oc < 180;
            pbv[mt][r] = ok ? pb[oc] : 0.f;
            nwv[mt][r] = ok ? nw[oc] : 0.f;
        }
    float ss[4] = {0.f, 0.f, 0.f, 0.f};
    #pragma unroll
    for (int mt = 0; mt < 3; mt++)
        #pragma unroll
        for (int pt = 0; pt < 4; pt++)
            #pragma unroll
            for (int r = 0; r < 4; r++) {
                float y = acc[mt][pt][r] + pbv[mt][r];
                acc[mt][pt][r] = y;
                ss[pt] = fmaf(y, y, ss[pt]);
            }
    #pragma unroll
    for (int pt = 0; pt < 4; pt++) {
        ss[pt] += __shfl_xor(ss[pt], 16);
        ss[pt] += __shfl_xor(ss[pt], 32);
    }
    if (q == 0) {
        #pragma unroll
        for (int pt = 0; pt < 4; pt++) part[g][pt][m] = ss[pt];
    }
    __syncthreads();
    float scale[4];
    #pragma unroll
    for (int pt = 0; pt < 4; pt++) {
        float tot = part[0][pt][m] + part[1][pt][m] + part[2][pt][m] + part[3][pt][m];
        scale[pt] = 1.0f / sqrtf(tot * (1.0f / 180.0f) + 1.1920929e-7f);
    }

    int bb = pix0 >> 16, sp0 = pix0 & 65535;
    const float* xb = x + (size_t)bb * 180 * HW + sp0 + m;
    float* ob = out + (size_t)bb * 180 * HW + sp0 + m;
    #pragma unroll
    for (int mt = 0; mt < 3; mt++)
        #pragma unroll
        for (int r = 0; r < 4; r++) {
            int oc = ocbase + mt * 16 + q * 4 + r;
            if (oc < 180) {
                #pragma unroll
                for (int pt = 0; pt < 4; pt++) {
                    size_t off = (size_t)oc * HW + pt * 16;
                    ob[off] = xb[off] + acc[mt][pt][r] * scale[pt] * nwv[mt][r];
                }
            }
        }
}

// ---------------------------------------------------------------------------
extern "C" void kernel_launch(void* const* d_in, const int* in_sizes, int n_in,
                              void* d_out, int out_size, void* d_ws, size_t ws_size,
                              hipStream_t stream)
{
    const float* x    = (const float*)d_in[0];
    const float* w1   = (const float*)d_in[1];
    const float* b1   = (const float*)d_in[2];
    const float* w2   = (const float*)d_in[3];
    const float* b2   = (const float*)d_in[4];
    const float* w3   = (const float*)d_in[5];
    const float* b3   = (const float*)d_in[6];
    const float* lw   = (const float*)d_in[7];
    const float* lb   = (const float*)d_in[8];
    const float* slw  = (const float*)d_in[9];
    const float* slb  = (const float*)d_in[10];
    const float* pw   = (const float*)d_in[11];
    const float* pb   = (const float*)d_in[12];
    const float* ln1w = (const float*)d_in[13];
    const float* ln1b = (const float*)d_in[14];
    const float* l1w  = (const float*)d_in[15];
    const float* l1b  = (const float*)d_in[16];
    const float* ln2w = (const float*)d_in[17];
    const float* ln2b = (const float*)d_in[18];
    const float* l2w  = (const float*)d_in[19];
    const float* l2b  = (const float*)d_in[20];
    const float* ln3w = (const float*)d_in[21];
    const float* ln3b = (const float*)d_in[22];
    const float* l3w  = (const float*)d_in[23];
    const float* l3b  = (const float*)d_in[24];
    const float* pjw  = (const float*)d_in[25];
    const float* pjb  = (const float*)d_in[26];
    const float* nw   = (const float*)d_in[27];
    float* out = (float*)d_out;

    char* ws = (char*)d_ws;
    // layout (time-disjoint overlap: qvT reuses dead h1 region; whiT/wloT
    // reuse dead h2 region after k_gate; gate weights live at the head of the
    // yp region, which is only written by k_spat/k_chan AFTER k_gate is done)
    float* pos = (float*)(ws + 0);            // 23 KB
    float* rpb = (float*)(ws + 24576);        // 384 KB  -> end 417792
    u16*  h2  = (u16*)(ws + 417792);          // 18.87 MB -> end 19292160
    u16*  whiT = (u16*)(ws + 417792);         // 72 KB (written AFTER k_gate)
    u16*  wloT = (u16*)(ws + 417792 + 73728); // 72 KB
    u16*  h1  = (u16*)(ws + 19292160);        // 18.87 MB -> end 38166528 (dead after conv3)
    u16*  qvT = (u16*)(ws + 19292160);        // 94.37 MB -> end 113664000 (written in k_gate)
    u16*  yp  = (u16*)(ws + 113664000);       // 100.66 MB -> end 214327296
    u16*  gwh = (u16*)(ws + 113664000);            // 73728 B  (dead once k_spat runs)
    u16*  gwl = (u16*)(ws + 113664000 + 73728);    // 73728 B
    u16*  cwh = (u16*)(ws + 113664000 + 147456);   // 24576 B
    u16*  cwl = (u16*)(ws + 113664000 + 172032);   // 24576 B -> end 113860608
    // total ws use: ~214.3 MB

    k_wgprep<<<dim3(192), dim3(256), 0, stream>>>(lw, w3, gwh, gwl, cwh, cwl);
    k_pos<<<dim3(1), dim3(1024), 0, stream>>>(pw, pb, ln1w, ln1b, l1w, l1b,
                                              ln2w, ln2b, l2w, l2b, ln3w, ln3b,
                                              l3w, l3b, pos);
    k_rpb<<<dim3(384), dim3(256), 0, stream>>>(pos, rpb);
    k_conv1<<<dim3(1024), dim3(256), 0, stream>>>(x, w1, b1, h1);
    k_conv3<<<dim3(16, 16, 4), dim3(16, 16), 0, stream>>>(h1, w2, b2, h2);
    k_gate<<<dim3(4096), dim3(256), 0, stream>>>(h2, x, gwh, gwl, cwh, cwl,
                                                 b3, lb, qvT);
    k_wprep<<<dim3(144), dim3(256), 0, stream>>>(pjw, whiT, wloT);   // h2 dead now
    k_spat<<<dim3(1024), dim3(256), 0, stream>>>(qvT, rpb, slw, slb, yp);
    k_chan<<<dim3(1024), dim3(256), 0, stream>>>(qvT, yp);
    k_proj<<<dim3(4096), dim3(256), 0, stream>>>(yp, x, whiT, wloT, pjb, nw, out);
}

// Round 3
// 1047.903 us; speedup vs baseline: 1.4593x; 1.0388x over previous
//
#include <hip/hip_runtime.h>
#include <stdint.h>

typedef unsigned short u16;
typedef unsigned int   u32;

#define HW 65536   // 256*256

typedef __bf16 bf16x8 __attribute__((ext_vector_type(8)));
typedef float  f32x4  __attribute__((ext_vector_type(4)));

static __device__ __forceinline__ float bf2f(u16 h) {
    u32 u = ((u32)h) << 16;
    return __builtin_bit_cast(float, u);
}
static __device__ __forceinline__ u16 f2bf(float f) {
    u32 u = __builtin_bit_cast(u32, f);
    u += 0x7fffu + ((u >> 16) & 1u);   // RNE
    return (u16)(u >> 16);
}
static __device__ __forceinline__ void bf2x2(u32 u, float& a, float& b) {
    a = __builtin_bit_cast(float, u << 16);
    b = __builtin_bit_cast(float, u & 0xffff0000u);
}
static __device__ __forceinline__ f32x4 mfma16(bf16x8 a, bf16x8 b, f32x4 c) {
    return __builtin_amdgcn_mfma_f32_16x16x32_bf16(a, b, c, 0, 0, 0);
}

// ---------------------------------------------------------------------------
// K0a: relative position bias MLP: (961,2) -> (961,6)
// ---------------------------------------------------------------------------
static __device__ __forceinline__ void lnrelu11(float* p, const float* __restrict__ w,
                                                const float* __restrict__ b) {
    float m = 0.f;
    #pragma unroll
    for (int k = 0; k < 11; k++) m += p[k];
    m *= (1.0f / 11.0f);
    float v = 0.f;
    #pragma unroll
    for (int k = 0; k < 11; k++) { float d = p[k] - m; v = fmaf(d, d, v); }
    v *= (1.0f / 11.0f);
    float r = 1.0f / sqrtf(v + 1e-5f);
    #pragma unroll
    for (int k = 0; k < 11; k++) {
        float t = (p[k] - m) * r * w[k] + b[k];
        p[k] = t > 0.f ? t : 0.f;
    }
}

__global__ __launch_bounds__(1024) void k_pos(
    const float* __restrict__ pw, const float* __restrict__ pb,
    const float* __restrict__ ln1w, const float* __restrict__ ln1b,
    const float* __restrict__ l1w, const float* __restrict__ l1b,
    const float* __restrict__ ln2w, const float* __restrict__ ln2b,
    const float* __restrict__ l2w, const float* __restrict__ l2b,
    const float* __restrict__ ln3w, const float* __restrict__ ln3b,
    const float* __restrict__ l3w, const float* __restrict__ l3b,
    float* __restrict__ pos)
{
    int i = threadIdx.x;
    if (i >= 961) return;
    float b0 = (float)(i / 31) - 15.0f;
    float b1 = (float)(i % 31) - 15.0f;
    float p[11], t[11];
    #pragma unroll
    for (int j = 0; j < 11; j++) p[j] = b0 * pw[j] + b1 * pw[11 + j] + pb[j];
    lnrelu11(p, ln1w, ln1b);
    #pragma unroll
    for (int j = 0; j < 11; j++) {
        float s = l1b[j];
        #pragma unroll
        for (int k = 0; k < 11; k++) s = fmaf(p[k], l1w[k * 11 + j], s);
        t[j] = s;
    }
    lnrelu11(t, ln2w, ln2b);
    #pragma unroll
    for (int j = 0; j < 11; j++) {
        float s = l2b[j];
        #pragma unroll
        for (int k = 0; k < 11; k++) s = fmaf(t[k], l2w[k * 11 + j], s);
        p[j] = s;
    }
    lnrelu11(p, ln3w, ln3b);
    #pragma unroll
    for (int h = 0; h < 6; h++) {
        float s = l3b[h];
        #pragma unroll
        for (int k = 0; k < 11; k++) s = fmaf(p[k], l3w[k * 6 + h], s);
        pos[i * 6 + h] = s;
    }
}

// ---------------------------------------------------------------------------
// K0b: rpb[h][l][m] = mean_r pos[idx(l, key(m,r))][h]   (6,256,64)
// ---------------------------------------------------------------------------
__global__ __launch_bounds__(256) void k_rpb(const float* __restrict__ pos,
                                             float* __restrict__ rpb)
{
    int g = blockIdx.x * 256 + threadIdx.x;
    if (g >= 6 * 256 * 64) return;
    int h = g >> 14;
    int l = (g >> 6) & 255;
    int m = g & 63;
    int yl = l >> 4, xl = l & 15;
    int my = m >> 3, mx = m & 7;
    float s = 0.f;
    #pragma unroll
    for (int ry = 0; ry < 2; ry++) {
        #pragma unroll
        for (int rx = 0; rx < 2; rx++) {
            int y2 = my * 2 + ry, x2 = mx * 2 + rx;
            int idx = (yl - y2 + 15) * 31 + (xl - x2 + 15);
            s += pos[idx * 6 + h];
        }
    }
    rpb[g] = 0.25f * s;
}

// ---------------------------------------------------------------------------
// K1: conv1x1 180->36 + lrelu.  x NCHW fp32 -> h1 planar bf16 [b][36][sp]
// ---------------------------------------------------------------------------
__global__ __launch_bounds__(256) void k_conv1(const float* __restrict__ x,
                                               const float* __restrict__ w,
                                               const float* __restrict__ b,
                                               u16* __restrict__ h1)
{
    int pix = blockIdx.x * 256 + threadIdx.x;
    int bb = pix >> 16, sp = pix & 65535;
    float acc[36];
    #pragma unroll
    for (int j = 0; j < 36; j++) acc[j] = b[j];
    const float* xp = x + (size_t)bb * 180 * HW + sp;
    for (int c = 0; c < 180; c++) {
        float xv = xp[(size_t)c * HW];
        #pragma unroll
        for (int j = 0; j < 36; j++) acc[j] = fmaf(xv, w[c * 36 + j], acc[j]);
    }
    u16* hp = h1 + (size_t)bb * 36 * HW + sp;
    #pragma unroll
    for (int j = 0; j < 36; j++) {
        float v = acc[j];
        v = v >= 0.f ? v : 0.2f * v;
        hp[(size_t)j * HW] = f2bf(v);
    }
}

// ---------------------------------------------------------------------------
// K2: conv3x3 36->36 pad1 + lrelu.  h1 planar bf16 -> h2 planar bf16
// ---------------------------------------------------------------------------
__global__ __launch_bounds__(256) void k_conv3(const u16* __restrict__ h1,
                                               const float* __restrict__ w,
                                               const float* __restrict__ b,
                                               u16* __restrict__ h2)
{
    int tx = threadIdx.x, ty = threadIdx.y;
    int x0 = blockIdx.x * 16 + tx;
    int y0 = blockIdx.y * 16 + ty;
    int bb = blockIdx.z;
    float acc[36];
    #pragma unroll
    for (int j = 0; j < 36; j++) acc[j] = b[j];
    const u16* base = h1 + (size_t)bb * 36 * HW;
    for (int ky = 0; ky < 3; ky++) {
        int yy = y0 + ky - 1;
        if (yy < 0 || yy >= 256) continue;
        for (int kx = 0; kx < 3; kx++) {
            int xx = x0 + kx - 1;
            if (xx < 0 || xx >= 256) continue;
            const u16* ip = base + yy * 256 + xx;
            const float* wp = w + ((ky * 3 + kx) * 36) * 36;
            for (int c = 0; c < 36; c++) {
                float v = bf2f(ip[(size_t)c * HW]);
                #pragma unroll
                for (int j = 0; j < 36; j++) acc[j] = fmaf(v, wp[c * 36 + j], acc[j]);
            }
        }
    }
    u16* op = h2 + (size_t)bb * 36 * HW + y0 * 256 + x0;
    #pragma unroll
    for (int j = 0; j < 36; j++) {
        float v = acc[j];
        v = v >= 0.f ? v : 0.2f * v;
        op[(size_t)j * HW] = f2bf(v);
    }
}

// ---------------------------------------------------------------------------
// K3a: weight prep for MFMA gate:
//   gating lw (180x180, [in][out]) -> gwh/gwl [oc:192][k:192] bf16 hi/lo
//   conv   w3 (36x180,  [in][out]) -> cwh/cwl [oc:192][k:64]  bf16 hi/lo
// ---------------------------------------------------------------------------
__global__ __launch_bounds__(256) void k_wgprep(const float* __restrict__ lw,
                                                const float* __restrict__ w3,
                                                u16* __restrict__ gwh,
                                                u16* __restrict__ gwl,
                                                u16* __restrict__ cwh,
                                                u16* __restrict__ cwl)
{
    int gidx = blockIdx.x * 256 + threadIdx.x;   // < 49152
    if (gidx < 36864) {
        int oc = gidx / 192, k = gidx % 192;
        float v = (oc < 180 && k < 180) ? lw[k * 180 + oc] : 0.f;
        u16 h = f2bf(v);
        float lo = v - bf2f(h);
        gwh[gidx] = h;
        gwl[gidx] = f2bf(lo);
    } else {
        int r = gidx - 36864;                    // < 12288
        int oc = r / 64, k = r % 64;
        float v = (oc < 180 && k < 36) ? w3[k * 180 + oc] : 0.f;
        u16 h = f2bf(v);
        float lo = v - bf2f(h);
        cwh[r] = h;
        cwl[r] = f2bf(lo);
    }
}

// ---------------------------------------------------------------------------
// K3: qv = (conv1x1 36->180 (h2) + b3) * (conv1x1 180->180 (x) + lb)
//     MFMA + LDS-staged inputs.
//     Block = quarter window (64 pixels); 4 waves x 48 oc each.
//     x tile staged via global_load_lds (1 KB/instruction -> full-BW MLP);
//     h2 tile staged via uint4 loads.  One-bit XOR swizzle (word ^=
//     ((c>>3)&1)<<4) applied on the pre-swizzled global source AND on LDS
//     reads turns the q-group 4-way bank conflict into a free 2-way.
// ---------------------------------------------------------------------------
__global__ __launch_bounds__(256) void k_gate(const u16* __restrict__ h2,
                                              const float* __restrict__ x,
                                              const u16* __restrict__ gwh,
                                              const u16* __restrict__ gwl,
                                              const u16* __restrict__ cwh,
                                              const u16* __restrict__ cwl,
                                              const float* __restrict__ b3,
                                              const float* __restrict__ lb,
                                              u16* __restrict__ qvT)
{
    __shared__ __align__(16) float xs[180 * 64];   // 46080 B, linear rows (swizzled content)
    __shared__ __align__(16) u16  hs[36 * 64];     // 4608 B
    int t = threadIdx.x;
    int lane = t & 63;
    int g = __builtin_amdgcn_readfirstlane(t >> 6);
    int m = lane & 15, q = lane >> 4;
    int blk = blockIdx.x;
    int w  = blk >> 2;                 // window index
    int lq = blk & 3;                  // quarter (4 rows) within window
    int bb = w >> 8, wy = (w >> 4) & 15, wx = w & 15;
    int ocb = g * 48;
    int y0 = wy * 16 + lq * 4;
    int xc0 = wx * 16;
    const float* xb = x + (size_t)bb * 180 * HW;
    const u16*  hb = h2 + (size_t)bb * 36 * HW;

    // ---- stage x tile: 45 x global_load_lds (width 16), rows c = 4s..4s+3 ----
    for (int s = g; s < 45; s += 4) {
        int c = s * 4 + (lane >> 4);
        int swz = (c >> 3) & 1;
        int pp = (lane & 15) ^ (swz << 2);      // 16B-chunk index within row
        int p0 = pp * 4;
        int prow = p0 >> 4, pcol = p0 & 15;
        const float* gp = xb + (size_t)c * HW + (y0 + prow) * 256 + xc0 + pcol;
        __builtin_amdgcn_global_load_lds(
            (const __attribute__((address_space(1))) void*)gp,
            (__attribute__((address_space(3))) void*)(xs + s * 256),
            16, 0, 0);
    }
    // ---- stage h2 tile: 288 uint4 chunks ----
    for (int idx = t; idx < 288; idx += 256) {
        int c = idx >> 3, j = idx & 7;
        int p0 = j * 8;                          // 8 u16 pixels
        int prow = p0 >> 4, pcol = p0 & 15;
        uint4 v = *(const uint4*)(hb + (size_t)c * HW + (y0 + prow) * 256 + xc0 + pcol);
        int swz = (c >> 3) & 1;
        *(uint4*)(hs + c * 64 + (p0 ^ (swz << 4))) = v;
    }
    __syncthreads();

    f32x4 accG[3][4], accC[3][4];
    #pragma unroll
    for (int mt = 0; mt < 3; mt++)
        #pragma unroll
        for (int pt = 0; pt < 4; pt++) {
            f32x4 z = {0.f, 0.f, 0.f, 0.f};
            accG[mt][pt] = z;
            accC[mt][pt] = z;
        }

    // ---- gating path: K = 192 (180 real) ----
    #pragma unroll 2
    for (int ks = 0; ks < 6; ks++) {
        bf16x8 Bh[4], Bl[4];
        #pragma unroll
        for (int pt = 0; pt < 4; pt++)
            #pragma unroll
            for (int j = 0; j < 8; j++) {
                int c = ks * 32 + q * 8 + j;
                if (c > 179) c = 179;            // pad rows have zero weights
                int p = pt * 16 + m;
                float v = xs[c * 64 + (p ^ (((c >> 3) & 1) << 4))];
                __bf16 hi = (__bf16)v;
                Bh[pt][j] = hi;
                Bl[pt][j] = (__bf16)(v - (float)hi);
            }
        #pragma unroll
        for (int mt = 0; mt < 3; mt++) {
            bf16x8 Ah = *(const bf16x8*)(gwh + (size_t)(ocb + mt * 16 + m) * 192 + ks * 32 + q * 8);
            bf16x8 Al = *(const bf16x8*)(gwl + (size_t)(ocb + mt * 16 + m) * 192 + ks * 32 + q * 8);
            #pragma unroll
            for (int pt = 0; pt < 4; pt++) {
                accG[mt][pt] = mfma16(Ah, Bh[pt], accG[mt][pt]);
                accG[mt][pt] = mfma16(Al, Bh[pt], accG[mt][pt]);
                accG[mt][pt] = mfma16(Ah, Bl[pt], accG[mt][pt]);
            }
        }
    }

    // ---- conv path: K = 64 (36 real), h2 already exact bf16 ----
    #pragma unroll
    for (int ks = 0; ks < 2; ks++) {
        bf16x8 B[4];
        #pragma unroll
        for (int pt = 0; pt < 4; pt++)
            #pragma unroll
            for (int j = 0; j < 8; j++) {
                int c = ks * 32 + q * 8 + j;
                if (c > 35) c = 35;              // pad rows have zero weights
                int p = pt * 16 + m;
                B[pt][j] = __builtin_bit_cast(__bf16, hs[c * 64 + (p ^ (((c >> 3) & 1) << 4))]);
            }
        #pragma unroll
        for (int mt = 0; mt < 3; mt++) {
            bf16x8 Ah = *(const bf16x8*)(cwh + (size_t)(ocb + mt * 16 + m) * 64 + ks * 32 + q * 8);
            bf16x8 Al = *(const bf16x8*)(cwl + (size_t)(ocb + mt * 16 + m) * 64 + ks * 32 + q * 8);
            #pragma unroll
            for (int pt = 0; pt < 4; pt++) {
                accC[mt][pt] = mfma16(Ah, B[pt], accC[mt][pt]);
                accC[mt][pt] = mfma16(Al, B[pt], accC[mt][pt]);
            }
        }
    }

    // ---- epilogue: bias, gate multiply, bf16 store to qvT[w][oc][l] ----
    u16* qw = qvT + (size_t)w * 180 * 256 + lq * 64 + m;
    #pragma unroll
    for (int mt = 0; mt < 3; mt++)
        #pragma unroll
        for (int r = 0; r < 4; r++) {
            int oc = ocb + mt * 16 + q * 4 + r;
            if (oc < 180) {
                float bc = b3[oc], bg = lb[oc];
                #pragma unroll
                for (int pt = 0; pt < 4; pt++) {
                    float ah = accC[mt][pt][r] + bc;
                    float al = accG[mt][pt][r] + bg;
                    qw[(size_t)oc * 256 + pt * 16] = f2bf(ah * al);
                }
            }
        }
}

// ---------------------------------------------------------------------------
// K4a: spatial attention per 16x16 window (reads qvT; writes yp slots 0..90)
//      Also zeroes yp slots 90..95 so k_proj can MFMA straight over [pix][192].
// ---------------------------------------------------------------------------
__global__ __launch_bounds__(256) void k_spat(const u16* __restrict__ qvT,
                                              const float* __restrict__ rpb,
                                              const float* __restrict__ slw,
                                              const float* __restrict__ slb,
                                              u16* __restrict__ yp)
{
    __shared__ __align__(16) float vp[6144];   // [6][64][16]
    int w = blockIdx.x;
    int bb = w >> 8, wy = (w >> 4) & 15, wx = w & 15;
    int t = threadIdx.x;
    int lane = t & 63, wv = t >> 6;
    const u16* qw = qvT + (size_t)w * 180 * 256;
    float s0 = slw[0], s1 = slw[1], s2 = slw[2], s3 = slw[3], sb = slb[0];
    // zero pad d=15
    for (int o = t; o < 384; o += 256) vp[(o >> 6) * 1024 + (o & 63) * 16 + 15] = 0.f;
    // vp staging: wave handles one (h,d) row (p = h*15+d), lane = m
    for (int it = 0; it < 23; it++) {
        int p = wv + it * 4;
        if (p < 90) {
            int mm = lane;
            int l0 = (mm >> 3) * 32 + (mm & 7) * 2;
            const u16* rp2 = qw + (size_t)(90 + p) * 256;
            float s = sb + s0 * bf2f(rp2[l0]) + s1 * bf2f(rp2[l0 + 1])
                         + s2 * bf2f(rp2[l0 + 16]) + s3 * bf2f(rp2[l0 + 17]);
            vp[(p / 15) * 1024 + mm * 16 + (p % 15)] = s;
        }
    }
    __syncthreads();
    int l = t;
    size_t pixl = (size_t)((bb * 256 + wy * 16 + (l >> 4)) * 256 + wx * 16 + (l & 15));
    u16* op = yp + pixl * 192;
    // zero pad slots 90..95 (uninitialized workspace could hold NaN patterns;
    // k_proj's MFMA K=192 multiplies them by zero weights, 0*NaN = NaN)
    ((u32*)op)[45] = 0u; ((u32*)op)[46] = 0u; ((u32*)op)[47] = 0u;
    for (int h = 0; h < 6; h++) {
        float q[16];
        #pragma unroll
        for (int d = 0; d < 15; d++) q[d] = bf2f(qw[(size_t)(h * 15 + d) * 256 + l]);
        q[15] = 0.f;
        float acc[16];
        #pragma unroll
        for (int d = 0; d < 16; d++) acc[d] = 0.f;
        const float* rp = rpb + ((h * 256 + l) << 6);
        const float4* vph = (const float4*)(vp + (h << 10));
        for (int m0 = 0; m0 < 64; m0 += 4) {
            float ra[4];
            *(float4*)ra = *(const float4*)(rp + m0);
            #pragma unroll
            for (int mm = 0; mm < 4; mm++) {
                int m = m0 + mm;
                float wvv[16];
                ((float4*)wvv)[0] = vph[m * 4 + 0];
                ((float4*)wvv)[1] = vph[m * 4 + 1];
                ((float4*)wvv)[2] = vph[m * 4 + 2];
                ((float4*)wvv)[3] = vph[m * 4 + 3];
                float s = 0.f;
                #pragma unroll
                for (int d2 = 0; d2 < 16; d2++) s = fmaf(q[d2], wvv[d2], s);
                s = s * (1.0f / 15.0f) + ra[mm];
                #pragma unroll
                for (int d2 = 0; d2 < 16; d2++) acc[d2] = fmaf(s, wvv[d2], acc[d2]);
            }
        }
        #pragma unroll
        for (int d = 0; d < 15; d++) op[h * 15 + d] = f2bf(acc[d]);
    }
}

// ---------------------------------------------------------------------------
// K4b: channel self-correlation per window — MFMA.
// ---------------------------------------------------------------------------
__global__ __launch_bounds__(256) void k_chan(const u16* __restrict__ qvT,
                                              u16* __restrict__ yp)
{
    __shared__ __align__(16) u16 cm[96 * 104];     // cmap bf16, stride 104
    __shared__ __align__(16) u16 xcb[128 * 104];   // xc half, stride 104
    int w = blockIdx.x;
    int bb = w >> 8, wy = (w >> 4) & 15, wx = w & 15;
    int t = threadIdx.x;
    int lane = t & 63, wv = t >> 6;
    int m = lane & 15, quad = lane >> 4;
    const u16* qw = qvT + (size_t)w * 180 * 256;

    // ---- phase 1: cmap ----
    int ct0 = (wv & 1) * 3, dt0 = (wv >> 1) * 3;
    f32x4 acc[3][3];
    #pragma unroll
    for (int i = 0; i < 3; i++)
        #pragma unroll
        for (int j = 0; j < 3; j++) {
            f32x4 z = {0.f, 0.f, 0.f, 0.f};
            acc[i][j] = z;
        }
    #pragma unroll
    for (int ks = 0; ks < 8; ks++) {
        bf16x8 A[3], B[3];
        #pragma unroll
        for (int i = 0; i < 3; i++)
            A[i] = *(const bf16x8*)(qw + (size_t)((ct0 + i) * 16 + m) * 256 + ks * 32 + quad * 8);
        #pragma unroll
        for (int j = 0; j < 3; j++) {
            int d = (dt0 + j) * 16 + m;
            int dd = d > 89 ? 89 : d;
            B[j] = *(const bf16x8*)(qw + (size_t)(90 + dd) * 256 + ks * 32 + quad * 8);
        }
        #pragma unroll
        for (int i = 0; i < 3; i++)
            #pragma unroll
            for (int j = 0; j < 3; j++)
                acc[i][j] = mfma16(A[i], B[j], acc[i][j]);
    }
    #pragma unroll
    for (int i = 0; i < 3; i++)
        #pragma unroll
        for (int j = 0; j < 3; j++)
            #pragma unroll
            for (int r = 0; r < 4; r++)
                cm[((ct0 + i) * 16 + quad * 4 + r) * 104 + (dt0 + j) * 16 + m] =
                    f2bf(acc[i][j][r] * (1.0f / 256.0f));
    __syncthreads();
    if (t < 96) {   // zero cmap columns 90..95 (pad garbage)
        u32* z = (u32*)(cm + t * 104 + 90);
        z[0] = 0; z[1] = 0; z[2] = 0;
    }
    __syncthreads();

    // ---- phase 2: xc, in two 128-row halves ----
    int base_pix = (bb * 256 + wy * 16) * 256 + wx * 16;
    const __bf16* qwb = (const __bf16*)qw;
    for (int half = 0; half < 2; half++) {
        #pragma unroll
        for (int i = 0; i < 2; i++) {
            int ltl = wv * 2 + i;           // 0..7
            int lt = half * 8 + ltl;
            bf16x8 A[3];
            #pragma unroll
            for (int ks = 0; ks < 3; ks++) {
                const __bf16* colp = qwb + lt * 16 + m;
                #pragma unroll
                for (int j2 = 0; j2 < 8; j2++) {
                    int d = ks * 32 + quad * 8 + j2;
                    int dd = d > 89 ? 89 : d;
                    A[ks][j2] = colp[(size_t)(90 + dd) * 256];
                }
            }
            for (int ct = 0; ct < 6; ct++) {
                f32x4 c4 = {0.f, 0.f, 0.f, 0.f};
                #pragma unroll
                for (int ks = 0; ks < 3; ks++) {
                    bf16x8 B = *(const bf16x8*)(cm + (ct * 16 + m) * 104 + ks * 32 + quad * 8);
                    c4 = mfma16(A[ks], B, c4);
                }
                #pragma unroll
                for (int r = 0; r < 4; r++)
                    xcb[(ltl * 16 + quad * 4 + r) * 104 + ct * 16 + m] = f2bf(c4[r]);
            }
        }
        __syncthreads();
        #pragma unroll
        for (int it = 0; it < 6; it++) {
            int gg = t + it * 256;          // < 1536
            int lrow = gg / 12, seg = gg % 12;
            int l = half * 128 + lrow;
            int pix = base_pix + (l >> 4) * 256 + (l & 15);
            *(uint4*)(yp + (size_t)pix * 192 + 96 + seg * 8) =
                *(const uint4*)(xcb + lrow * 104 + seg * 8);
        }
        __syncthreads();
    }
}

// ---------------------------------------------------------------------------
// K5a: weight prep for MFMA proj: pad proj_w (180x180) to [oc:192][k:192]
//      bf16 hi/lo split, transposed to A-fragment layout [oc][k].
// ---------------------------------------------------------------------------
__global__ __launch_bounds__(256) void k_wprep(const float* __restrict__ pjw,
                                               u16* __restrict__ whiT,
                                               u16* __restrict__ wloT)
{
    int g = blockIdx.x * 256 + threadIdx.x;    // < 36864 = 192*192
    int oc = g / 192, k = g % 192;
    int kp = -1;
    if (k < 90) kp = k;
    else if (k >= 96 && k <= 185) kp = k - 6;
    float v = (kp >= 0 && oc < 180) ? pjw[kp * 180 + oc] : 0.f;
    u16 h = f2bf(v);
    float lo = v - bf2f(h);                    // exact (Sterbenz)
    whiT[g] = h;
    wloT[g] = f2bf(lo);
}

// ---------------------------------------------------------------------------
// K5: y = y_pre @ proj_w + proj_b ; RMSNorm ; + shortcut(x) ; write NCHW fp32
//     MFMA main loop unchanged.  NEW epilogue: LDS-transposed 2-phase so the
//     x shortcut loads and out stores are dwordx4 (16B/vmcnt-slot, 4x MLP).
// ---------------------------------------------------------------------------
__global__ __launch_bounds__(256) void k_proj(const u16* __restrict__ yp,
                                              const float* __restrict__ x,
                                              const u16* __restrict__ whiT,
                                              const u16* __restrict__ wloT,
                                              const float* __restrict__ pb,
                                              const float* __restrict__ nw,
                                              float* __restrict__ out)
{
    __shared__ __align__(16) float st[96 * 68];   // 26112 B staging half
    __shared__ float part[4][4][16];
    int t = threadIdx.x;
    int lane = t & 63;
    int g = __builtin_amdgcn_readfirstlane(t >> 6);
    int m = lane & 15, q = lane >> 4;
    int pix0 = blockIdx.x * 64;
    int ocbase = g * 48;

    f32x4 acc[3][4];
    #pragma unroll
    for (int mt = 0; mt < 3; mt++)
        #pragma unroll
        for (int pt = 0; pt < 4; pt++) {
            f32x4 z = {0.f, 0.f, 0.f, 0.f};
            acc[mt][pt] = z;
        }

    const u16* bbase = yp + (size_t)pix0 * 192;
    #pragma unroll 2
    for (int ks = 0; ks < 6; ks++) {
        bf16x8 B[4];
        #pragma unroll
        for (int pt = 0; pt < 4; pt++)
            B[pt] = *(const bf16x8*)(bbase + (size_t)(pt * 16 + m) * 192 + ks * 32 + q * 8);
        #pragma unroll
        for (int mt = 0; mt < 3; mt++) {
            bf16x8 Ah = *(const bf16x8*)(whiT + (size_t)(ocbase + mt * 16 + m) * 192 + ks * 32 + q * 8);
            bf16x8 Al = *(const bf16x8*)(wloT + (size_t)(ocbase + mt * 16 + m) * 192 + ks * 32 + q * 8);
            #pragma unroll
            for (int pt = 0; pt < 4; pt++) {
                acc[mt][pt] = mfma16(Ah, B[pt], acc[mt][pt]);
                acc[mt][pt] = mfma16(Al, B[pt], acc[mt][pt]);
            }
        }
    }

    // ---- epilogue: bias, per-pixel RMS ----
    float pbv[3][4], nwv[3][4];
    #pragma unroll
    for (int mt = 0; mt < 3; mt++)
        #pragma unroll
        for (int r = 0; r < 4; r++) {
            int oc = ocbase + mt * 16 + q * 4 + r;
            bool ok = oc < 180;
            pbv[mt][r] = ok ? pb[oc] : 0.f;
            nwv[mt][r] = ok ? nw[oc] : 0.f;
        }
    float ss[4] = {0.f, 0.f, 0.f, 0.f};
    #pragma unroll
    for (int mt = 0; mt < 3; mt++)
        #pragma unroll
        for (int pt = 0; pt < 4; pt++)
            #pragma unroll
            for (int r = 0; r < 4; r++) {
                float y = acc[mt][pt][r] + pbv[mt][r];
                acc[mt][pt][r] = y;
                ss[pt] = fmaf(y, y, ss[pt]);
            }
    #pragma unroll
    for (int pt = 0; pt < 4; pt++) {
        ss[pt] += __shfl_xor(ss[pt], 16);
        ss[pt] += __shfl_xor(ss[pt], 32);
    }
    if (q == 0) {
        #pragma unroll
        for (int pt = 0; pt < 4; pt++) part[g][pt][m] = ss[pt];
    }
    __syncthreads();
    float scale[4];
    #pragma unroll
    for (int pt = 0; pt < 4; pt++) {
        float tot = part[0][pt][m] + part[1][pt][m] + part[2][pt][m] + part[3][pt][m];
        scale[pt] = 1.0f / sqrtf(tot * (1.0f / 180.0f) + 1.1920929e-7f);
    }
    // fold scale*nw into acc (final contribution values)
    #pragma unroll
    for (int mt = 0; mt < 3; mt++)
        #pragma unroll
        for (int pt = 0; pt < 4; pt++)
            #pragma unroll
            for (int r = 0; r < 4; r++)
                acc[mt][pt][r] = acc[mt][pt][r] * scale[pt] * nwv[mt][r];

    // ---- 2-phase LDS transpose; dwordx4 x-load + add + dwordx4 store ----
    int bb = pix0 >> 16, sp0 = pix0 & 65535;
    const float* xb = x + (size_t)bb * 180 * HW + sp0;
    float* ob = out + (size_t)bb * 180 * HW + sp0;
    #pragma unroll
    for (int ph = 0; ph < 2; ph++) {
        if ((g >> 1) == ph) {
            int rb = (g & 1) * 48;
            #pragma unroll
            for (int mt = 0; mt < 3; mt++)
                #pragma unroll
                for (int r = 0; r < 4; r++) {
                    int row = rb + mt * 16 + q * 4 + r;
                    #pragma unroll
                    for (int pt = 0; pt < 4; pt++)
                        st[row * 68 + pt * 16 + m] = acc[mt][pt][r];
                }
        }
        __syncthreads();
        int nch = ph ? 1344 : 1536;        // rows*16 (phase B: oc 96..179)
        for (int i = t; i < nch; i += 256) {
            int row = i >> 4, j = i & 15;
            int oc = ph * 96 + row;
            f32x4 d = *(const f32x4*)(st + row * 68 + j * 4);
            size_t off = (size_t)oc * HW + j * 4;
            f32x4 xv = *(const f32x4*)(xb + off);
            *(f32x4*)(ob + off) = d + xv;
        }
        __syncthreads();
    }
}

// ---------------------------------------------------------------------------
extern "C" void kernel_launch(void* const* d_in, const int* in_sizes, int n_in,
                              void* d_out, int out_size, void* d_ws, size_t ws_size,
                              hipStream_t stream)
{
    const float* x    = (const float*)d_in[0];
    const float* w1   = (const float*)d_in[1];
    const float* b1   = (const float*)d_in[2];
    const float* w2   = (const float*)d_in[3];
    const float* b2   = (const float*)d_in[4];
    const float* w3   = (const float*)d_in[5];
    const float* b3   = (const float*)d_in[6];
    const float* lw   = (const float*)d_in[7];
    const float* lb   = (const float*)d_in[8];
    const float* slw  = (const float*)d_in[9];
    const float* slb  = (const float*)d_in[10];
    const float* pw   = (const float*)d_in[11];
    const float* pb   = (const float*)d_in[12];
    const float* ln1w = (const float*)d_in[13];
    const float* ln1b = (const float*)d_in[14];
    const float* l1w  = (const float*)d_in[15];
    const float* l1b  = (const float*)d_in[16];
    const float* ln2w = (const float*)d_in[17];
    const float* ln2b = (const float*)d_in[18];
    const float* l2w  = (const float*)d_in[19];
    const float* l2b  = (const float*)d_in[20];
    const float* ln3w = (const float*)d_in[21];
    const float* ln3b = (const float*)d_in[22];
    const float* l3w  = (const float*)d_in[23];
    const float* l3b  = (const float*)d_in[24];
    const float* pjw  = (const float*)d_in[25];
    const float* pjb  = (const float*)d_in[26];
    const float* nw   = (const float*)d_in[27];
    float* out = (float*)d_out;

    char* ws = (char*)d_ws;
    // layout (time-disjoint overlap: qvT reuses dead h1 region; whiT/wloT
    // reuse dead h2 region after k_gate; gate weights live at the head of the
    // yp region, which is only written by k_spat/k_chan AFTER k_gate is done)
    float* pos = (float*)(ws + 0);            // 23 KB
    float* rpb = (float*)(ws + 24576);        // 384 KB  -> end 417792
    u16*  h2  = (u16*)(ws + 417792);          // 18.87 MB -> end 19292160
    u16*  whiT = (u16*)(ws + 417792);         // 72 KB (written AFTER k_gate)
    u16*  wloT = (u16*)(ws + 417792 + 73728); // 72 KB
    u16*  h1  = (u16*)(ws + 19292160);        // 18.87 MB -> end 38166528 (dead after conv3)
    u16*  qvT = (u16*)(ws + 19292160);        // 94.37 MB -> end 113664000 (written in k_gate)
    u16*  yp  = (u16*)(ws + 113664000);       // 100.66 MB -> end 214327296
    u16*  gwh = (u16*)(ws + 113664000);            // 73728 B  (dead once k_spat runs)
    u16*  gwl = (u16*)(ws + 113664000 + 73728);    // 73728 B
    u16*  cwh = (u16*)(ws + 113664000 + 147456);   // 24576 B
    u16*  cwl = (u16*)(ws + 113664000 + 172032);   // 24576 B -> end 113860608
    // total ws use: ~214.3 MB

    k_wgprep<<<dim3(192), dim3(256), 0, stream>>>(lw, w3, gwh, gwl, cwh, cwl);
    k_pos<<<dim3(1), dim3(1024), 0, stream>>>(pw, pb, ln1w, ln1b, l1w, l1b,
                                              ln2w, ln2b, l2w, l2b, ln3w, ln3b,
                                              l3w, l3b, pos);
    k_rpb<<<dim3(384), dim3(256), 0, stream>>>(pos, rpb);
    k_conv1<<<dim3(1024), dim3(256), 0, stream>>>(x, w1, b1, h1);
    k_conv3<<<dim3(16, 16, 4), dim3(16, 16), 0, stream>>>(h1, w2, b2, h2);
    k_gate<<<dim3(4096), dim3(256), 0, stream>>>(h2, x, gwh, gwl, cwh, cwl,
                                                 b3, lb, qvT);
    k_wprep<<<dim3(144), dim3(256), 0, stream>>>(pjw, whiT, wloT);   // h2 dead now
    k_spat<<<dim3(1024), dim3(256), 0, stream>>>(qvT, rpb, slw, slb, yp);
    k_chan<<<dim3(1024), dim3(256), 0, stream>>>(qvT, yp);
    k_proj<<<dim3(4096), dim3(256), 0, stream>>>(yp, x, whiT, wloT, pjb, nw, out);
}

// Round 4
// 1024.914 us; speedup vs baseline: 1.4921x; 1.0224x over previous
//
#include <hip/hip_runtime.h>
#include <stdint.h>

typedef unsigned short u16;
typedef unsigned int   u32;

#define HW 65536   // 256*256

typedef __bf16 bf16x8 __attribute__((ext_vector_type(8)));
typedef float  f32x4  __attribute__((ext_vector_type(4)));

static __device__ __forceinline__ float bf2f(u16 h) {
    u32 u = ((u32)h) << 16;
    return __builtin_bit_cast(float, u);
}
static __device__ __forceinline__ u16 f2bf(float f) {
    u32 u = __builtin_bit_cast(u32, f);
    u += 0x7fffu + ((u >> 16) & 1u);   // RNE
    return (u16)(u >> 16);
}
static __device__ __forceinline__ void bf2x2(u32 u, float& a, float& b) {
    a = __builtin_bit_cast(float, u << 16);
    b = __builtin_bit_cast(float, u & 0xffff0000u);
}
static __device__ __forceinline__ f32x4 mfma16(bf16x8 a, bf16x8 b, f32x4 c) {
    return __builtin_amdgcn_mfma_f32_16x16x32_bf16(a, b, c, 0, 0, 0);
}

// ---------------------------------------------------------------------------
// K0a: relative position bias MLP: (961,2) -> (961,6)
// ---------------------------------------------------------------------------
static __device__ __forceinline__ void lnrelu11(float* p, const float* __restrict__ w,
                                                const float* __restrict__ b) {
    float m = 0.f;
    #pragma unroll
    for (int k = 0; k < 11; k++) m += p[k];
    m *= (1.0f / 11.0f);
    float v = 0.f;
    #pragma unroll
    for (int k = 0; k < 11; k++) { float d = p[k] - m; v = fmaf(d, d, v); }
    v *= (1.0f / 11.0f);
    float r = 1.0f / sqrtf(v + 1e-5f);
    #pragma unroll
    for (int k = 0; k < 11; k++) {
        float t = (p[k] - m) * r * w[k] + b[k];
        p[k] = t > 0.f ? t : 0.f;
    }
}

__global__ __launch_bounds__(1024) void k_pos(
    const float* __restrict__ pw, const float* __restrict__ pb,
    const float* __restrict__ ln1w, const float* __restrict__ ln1b,
    const float* __restrict__ l1w, const float* __restrict__ l1b,
    const float* __restrict__ ln2w, const float* __restrict__ ln2b,
    const float* __restrict__ l2w, const float* __restrict__ l2b,
    const float* __restrict__ ln3w, const float* __restrict__ ln3b,
    const float* __restrict__ l3w, const float* __restrict__ l3b,
    float* __restrict__ pos)
{
    int i = threadIdx.x;
    if (i >= 961) return;
    float b0 = (float)(i / 31) - 15.0f;
    float b1 = (float)(i % 31) - 15.0f;
    float p[11], t[11];
    #pragma unroll
    for (int j = 0; j < 11; j++) p[j] = b0 * pw[j] + b1 * pw[11 + j] + pb[j];
    lnrelu11(p, ln1w, ln1b);
    #pragma unroll
    for (int j = 0; j < 11; j++) {
        float s = l1b[j];
        #pragma unroll
        for (int k = 0; k < 11; k++) s = fmaf(p[k], l1w[k * 11 + j], s);
        t[j] = s;
    }
    lnrelu11(t, ln2w, ln2b);
    #pragma unroll
    for (int j = 0; j < 11; j++) {
        float s = l2b[j];
        #pragma unroll
        for (int k = 0; k < 11; k++) s = fmaf(t[k], l2w[k * 11 + j], s);
        p[j] = s;
    }
    lnrelu11(p, ln3w, ln3b);
    #pragma unroll
    for (int h = 0; h < 6; h++) {
        float s = l3b[h];
        #pragma unroll
        for (int k = 0; k < 11; k++) s = fmaf(p[k], l3w[k * 6 + h], s);
        pos[i * 6 + h] = s;
    }
}

// ---------------------------------------------------------------------------
// K0b: rpb[h][l][m] = mean_r pos[idx(l, key(m,r))][h]   (6,256,64)
// ---------------------------------------------------------------------------
__global__ __launch_bounds__(256) void k_rpb(const float* __restrict__ pos,
                                             float* __restrict__ rpb)
{
    int g = blockIdx.x * 256 + threadIdx.x;
    if (g >= 6 * 256 * 64) return;
    int h = g >> 14;
    int l = (g >> 6) & 255;
    int m = g & 63;
    int yl = l >> 4, xl = l & 15;
    int my = m >> 3, mx = m & 7;
    float s = 0.f;
    #pragma unroll
    for (int ry = 0; ry < 2; ry++) {
        #pragma unroll
        for (int rx = 0; rx < 2; rx++) {
            int y2 = my * 2 + ry, x2 = mx * 2 + rx;
            int idx = (yl - y2 + 15) * 31 + (xl - x2 + 15);
            s += pos[idx * 6 + h];
        }
    }
    rpb[g] = 0.25f * s;
}

// ---------------------------------------------------------------------------
// K1: conv1x1 180->36 + lrelu.  x NCHW fp32 -> h1 planar bf16 [b][36][sp]
// ---------------------------------------------------------------------------
__global__ __launch_bounds__(256) void k_conv1(const float* __restrict__ x,
                                               const float* __restrict__ w,
                                               const float* __restrict__ b,
                                               u16* __restrict__ h1)
{
    int pix = blockIdx.x * 256 + threadIdx.x;
    int bb = pix >> 16, sp = pix & 65535;
    float acc[36];
    #pragma unroll
    for (int j = 0; j < 36; j++) acc[j] = b[j];
    const float* xp = x + (size_t)bb * 180 * HW + sp;
    for (int c = 0; c < 180; c++) {
        float xv = xp[(size_t)c * HW];
        #pragma unroll
        for (int j = 0; j < 36; j++) acc[j] = fmaf(xv, w[c * 36 + j], acc[j]);
    }
    u16* hp = h1 + (size_t)bb * 36 * HW + sp;
    #pragma unroll
    for (int j = 0; j < 36; j++) {
        float v = acc[j];
        v = v >= 0.f ? v : 0.2f * v;
        hp[(size_t)j * HW] = f2bf(v);
    }
}

// ---------------------------------------------------------------------------
// K2: conv3x3 36->36 pad1 + lrelu.  h1 planar bf16 -> h2 planar bf16
// ---------------------------------------------------------------------------
__global__ __launch_bounds__(256) void k_conv3(const u16* __restrict__ h1,
                                               const float* __restrict__ w,
                                               const float* __restrict__ b,
                                               u16* __restrict__ h2)
{
    int tx = threadIdx.x, ty = threadIdx.y;
    int x0 = blockIdx.x * 16 + tx;
    int y0 = blockIdx.y * 16 + ty;
    int bb = blockIdx.z;
    float acc[36];
    #pragma unroll
    for (int j = 0; j < 36; j++) acc[j] = b[j];
    const u16* base = h1 + (size_t)bb * 36 * HW;
    for (int ky = 0; ky < 3; ky++) {
        int yy = y0 + ky - 1;
        if (yy < 0 || yy >= 256) continue;
        for (int kx = 0; kx < 3; kx++) {
            int xx = x0 + kx - 1;
            if (xx < 0 || xx >= 256) continue;
            const u16* ip = base + yy * 256 + xx;
            const float* wp = w + ((ky * 3 + kx) * 36) * 36;
            for (int c = 0; c < 36; c++) {
                float v = bf2f(ip[(size_t)c * HW]);
                #pragma unroll
                for (int j = 0; j < 36; j++) acc[j] = fmaf(v, wp[c * 36 + j], acc[j]);
            }
        }
    }
    u16* op = h2 + (size_t)bb * 36 * HW + y0 * 256 + x0;
    #pragma unroll
    for (int j = 0; j < 36; j++) {
        float v = acc[j];
        v = v >= 0.f ? v : 0.2f * v;
        op[(size_t)j * HW] = f2bf(v);
    }
}

// ---------------------------------------------------------------------------
// K3a: weight prep for MFMA gate:
//   gating lw (180x180, [in][out]) -> gwh/gwl [oc:192][k:192] bf16 hi/lo
//   conv   w3 (36x180,  [in][out]) -> cwh/cwl [oc:192][k:64]  bf16 hi/lo
// ---------------------------------------------------------------------------
__global__ __launch_bounds__(256) void k_wgprep(const float* __restrict__ lw,
                                                const float* __restrict__ w3,
                                                u16* __restrict__ gwh,
                                                u16* __restrict__ gwl,
                                                u16* __restrict__ cwh,
                                                u16* __restrict__ cwl)
{
    int gidx = blockIdx.x * 256 + threadIdx.x;   // < 49152
    if (gidx < 36864) {
        int oc = gidx / 192, k = gidx % 192;
        float v = (oc < 180 && k < 180) ? lw[k * 180 + oc] : 0.f;
        u16 h = f2bf(v);
        float lo = v - bf2f(h);
        gwh[gidx] = h;
        gwl[gidx] = f2bf(lo);
    } else {
        int r = gidx - 36864;                    // < 12288
        int oc = r / 64, k = r % 64;
        float v = (oc < 180 && k < 36) ? w3[k * 180 + oc] : 0.f;
        u16 h = f2bf(v);
        float lo = v - bf2f(h);
        cwh[r] = h;
        cwl[r] = f2bf(lo);
    }
}

// ---------------------------------------------------------------------------
// K3: qv = (conv1x1 36->180 (h2) + b3) * (conv1x1 180->180 (x) + lb)
//     MFMA + LDS-staged inputs.  NEW: epilogue restages the output tile in
//     LDS (reusing dead xs) so qvT stores are full-line coalesced uint4
//     instead of 48 scattered 32B segments per thread.
// ---------------------------------------------------------------------------
__global__ __launch_bounds__(256) void k_gate(const u16* __restrict__ h2,
                                              const float* __restrict__ x,
                                              const u16* __restrict__ gwh,
                                              const u16* __restrict__ gwl,
                                              const u16* __restrict__ cwh,
                                              const u16* __restrict__ cwl,
                                              const float* __restrict__ b3,
                                              const float* __restrict__ lb,
                                              u16* __restrict__ qvT)
{
    __shared__ __align__(16) float xs[180 * 64];   // 46080 B; reused as out-tile
    __shared__ __align__(16) u16  hs[36 * 64];     // 4608 B
    int t = threadIdx.x;
    int lane = t & 63;
    int g = __builtin_amdgcn_readfirstlane(t >> 6);
    int m = lane & 15, q = lane >> 4;
    int blk = blockIdx.x;
    int w  = blk >> 2;                 // window index
    int lq = blk & 3;                  // quarter (4 rows) within window
    int bb = w >> 8, wy = (w >> 4) & 15, wx = w & 15;
    int ocb = g * 48;
    int y0 = wy * 16 + lq * 4;
    int xc0 = wx * 16;
    const float* xb = x + (size_t)bb * 180 * HW;
    const u16*  hb = h2 + (size_t)bb * 36 * HW;

    // ---- stage x tile: 45 x global_load_lds (width 16), rows c = 4s..4s+3 ----
    for (int s = g; s < 45; s += 4) {
        int c = s * 4 + (lane >> 4);
        int swz = (c >> 3) & 1;
        int pp = (lane & 15) ^ (swz << 2);      // 16B-chunk index within row
        int p0 = pp * 4;
        int prow = p0 >> 4, pcol = p0 & 15;
        const float* gp = xb + (size_t)c * HW + (y0 + prow) * 256 + xc0 + pcol;
        __builtin_amdgcn_global_load_lds(
            (const __attribute__((address_space(1))) void*)gp,
            (__attribute__((address_space(3))) void*)(xs + s * 256),
            16, 0, 0);
    }
    // ---- stage h2 tile: 288 uint4 chunks ----
    for (int idx = t; idx < 288; idx += 256) {
        int c = idx >> 3, j = idx & 7;
        int p0 = j * 8;                          // 8 u16 pixels
        int prow = p0 >> 4, pcol = p0 & 15;
        uint4 v = *(const uint4*)(hb + (size_t)c * HW + (y0 + prow) * 256 + xc0 + pcol);
        int swz = (c >> 3) & 1;
        *(uint4*)(hs + c * 64 + (p0 ^ (swz << 4))) = v;
    }
    __syncthreads();

    f32x4 accG[3][4], accC[3][4];
    #pragma unroll
    for (int mt = 0; mt < 3; mt++)
        #pragma unroll
        for (int pt = 0; pt < 4; pt++) {
            f32x4 z = {0.f, 0.f, 0.f, 0.f};
            accG[mt][pt] = z;
            accC[mt][pt] = z;
        }

    // ---- gating path: K = 192 (180 real) ----
    #pragma unroll 2
    for (int ks = 0; ks < 6; ks++) {
        bf16x8 Bh[4], Bl[4];
        #pragma unroll
        for (int pt = 0; pt < 4; pt++)
            #pragma unroll
            for (int j = 0; j < 8; j++) {
                int c = ks * 32 + q * 8 + j;
                if (c > 179) c = 179;            // pad rows have zero weights
                int p = pt * 16 + m;
                float v = xs[c * 64 + (p ^ (((c >> 3) & 1) << 4))];
                __bf16 hi = (__bf16)v;
                Bh[pt][j] = hi;
                Bl[pt][j] = (__bf16)(v - (float)hi);
            }
        #pragma unroll
        for (int mt = 0; mt < 3; mt++) {
            bf16x8 Ah = *(const bf16x8*)(gwh + (size_t)(ocb + mt * 16 + m) * 192 + ks * 32 + q * 8);
            bf16x8 Al = *(const bf16x8*)(gwl + (size_t)(ocb + mt * 16 + m) * 192 + ks * 32 + q * 8);
            #pragma unroll
            for (int pt = 0; pt < 4; pt++) {
                accG[mt][pt] = mfma16(Ah, Bh[pt], accG[mt][pt]);
                accG[mt][pt] = mfma16(Al, Bh[pt], accG[mt][pt]);
                accG[mt][pt] = mfma16(Ah, Bl[pt], accG[mt][pt]);
            }
        }
    }

    // ---- conv path: K = 64 (36 real), h2 already exact bf16 ----
    #pragma unroll
    for (int ks = 0; ks < 2; ks++) {
        bf16x8 B[4];
        #pragma unroll
        for (int pt = 0; pt < 4; pt++)
            #pragma unroll
            for (int j = 0; j < 8; j++) {
                int c = ks * 32 + q * 8 + j;
                if (c > 35) c = 35;              // pad rows have zero weights
                int p = pt * 16 + m;
                B[pt][j] = __builtin_bit_cast(__bf16, hs[c * 64 + (p ^ (((c >> 3) & 1) << 4))]);
            }
        #pragma unroll
        for (int mt = 0; mt < 3; mt++) {
            bf16x8 Ah = *(const bf16x8*)(cwh + (size_t)(ocb + mt * 16 + m) * 64 + ks * 32 + q * 8);
            bf16x8 Al = *(const bf16x8*)(cwl + (size_t)(ocb + mt * 16 + m) * 64 + ks * 32 + q * 8);
            #pragma unroll
            for (int pt = 0; pt < 4; pt++) {
                accC[mt][pt] = mfma16(Ah, B[pt], accC[mt][pt]);
                accC[mt][pt] = mfma16(Al, B[pt], accC[mt][pt]);
            }
        }
    }

    // ---- epilogue: bias, gate multiply -> LDS tile [180][66] -> coalesced out
    __syncthreads();                     // xs/hs reads all done; reuse xs
    u16* qtile = (u16*)xs;               // [180][66] u16 = 23760 B
    #pragma unroll
    for (int mt = 0; mt < 3; mt++)
        #pragma unroll
        for (int r = 0; r < 4; r++) {
            int oc = ocb + mt * 16 + q * 4 + r;
            if (oc < 180) {
                float bc = b3[oc], bg = lb[oc];
                #pragma unroll
                for (int pt = 0; pt < 4; pt++) {
                    float ah = accC[mt][pt][r] + bc;
                    float al = accG[mt][pt][r] + bg;
                    qtile[oc * 66 + pt * 16 + m] = f2bf(ah * al);
                }
            }
        }
    __syncthreads();
    u16* qbase = qvT + (size_t)w * 180 * 256 + lq * 64;
    for (int i = t; i < 1440; i += 256) {      // 180 oc x 8 chunks of 16B
        int oc = i >> 3, ch = i & 7;
        *(uint4*)(qbase + (size_t)oc * 256 + ch * 8) =
            *(const uint4*)(qtile + oc * 66 + ch * 8);
    }
}

// ---------------------------------------------------------------------------
// K4a: spatial attention per 16x16 window (reads qvT; writes yp slots 0..90)
//      Also zeroes yp slots 90..95 so k_proj can MFMA straight over [pix][192].
// ---------------------------------------------------------------------------
__global__ __launch_bounds__(256) void k_spat(const u16* __restrict__ qvT,
                                              const float* __restrict__ rpb,
                                              const float* __restrict__ slw,
                                              const float* __restrict__ slb,
                                              u16* __restrict__ yp)
{
    __shared__ __align__(16) float vp[6144];   // [6][64][16]
    int w = blockIdx.x;
    int bb = w >> 8, wy = (w >> 4) & 15, wx = w & 15;
    int t = threadIdx.x;
    int lane = t & 63, wv = t >> 6;
    const u16* qw = qvT + (size_t)w * 180 * 256;
    float s0 = slw[0], s1 = slw[1], s2 = slw[2], s3 = slw[3], sb = slb[0];
    // zero pad d=15
    for (int o = t; o < 384; o += 256) vp[(o >> 6) * 1024 + (o & 63) * 16 + 15] = 0.f;
    // vp staging: wave handles one (h,d) row (p = h*15+d), lane = m
    for (int it = 0; it < 23; it++) {
        int p = wv + it * 4;
        if (p < 90) {
            int mm = lane;
            int l0 = (mm >> 3) * 32 + (mm & 7) * 2;
            const u16* rp2 = qw + (size_t)(90 + p) * 256;
            float s = sb + s0 * bf2f(rp2[l0]) + s1 * bf2f(rp2[l0 + 1])
                         + s2 * bf2f(rp2[l0 + 16]) + s3 * bf2f(rp2[l0 + 17]);
            vp[(p / 15) * 1024 + mm * 16 + (p % 15)] = s;
        }
    }
    __syncthreads();
    int l = t;
    size_t pixl = (size_t)((bb * 256 + wy * 16 + (l >> 4)) * 256 + wx * 16 + (l & 15));
    u16* op = yp + pixl * 192;
    // zero pad slots 90..95 (uninitialized workspace could hold NaN patterns;
    // k_proj's MFMA K=192 multiplies them by zero weights, 0*NaN = NaN)
    ((u32*)op)[45] = 0u; ((u32*)op)[46] = 0u; ((u32*)op)[47] = 0u;
    for (int h = 0; h < 6; h++) {
        float q[16];
        #pragma unroll
        for (int d = 0; d < 15; d++) q[d] = bf2f(qw[(size_t)(h * 15 + d) * 256 + l]);
        q[15] = 0.f;
        float acc[16];
        #pragma unroll
        for (int d = 0; d < 16; d++) acc[d] = 0.f;
        const float* rp = rpb + ((h * 256 + l) << 6);
        const float4* vph = (const float4*)(vp + (h << 10));
        for (int m0 = 0; m0 < 64; m0 += 4) {
            float ra[4];
            *(float4*)ra = *(const float4*)(rp + m0);
            #pragma unroll
            for (int mm = 0; mm < 4; mm++) {
                int m = m0 + mm;
                float wvv[16];
                ((float4*)wvv)[0] = vph[m * 4 + 0];
                ((float4*)wvv)[1] = vph[m * 4 + 1];
                ((float4*)wvv)[2] = vph[m * 4 + 2];
                ((float4*)wvv)[3] = vph[m * 4 + 3];
                float s = 0.f;
                #pragma unroll
                for (int d2 = 0; d2 < 16; d2++) s = fmaf(q[d2], wvv[d2], s);
                s = s * (1.0f / 15.0f) + ra[mm];
                #pragma unroll
                for (int d2 = 0; d2 < 16; d2++) acc[d2] = fmaf(s, wvv[d2], acc[d2]);
            }
        }
        #pragma unroll
        for (int d = 0; d < 15; d++) op[h * 15 + d] = f2bf(acc[d]);
    }
}

// ---------------------------------------------------------------------------
// K4b: channel self-correlation per window — MFMA.
// ---------------------------------------------------------------------------
__global__ __launch_bounds__(256) void k_chan(const u16* __restrict__ qvT,
                                              u16* __restrict__ yp)
{
    __shared__ __align__(16) u16 cm[96 * 104];     // cmap bf16, stride 104
    __shared__ __align__(16) u16 xcb[128 * 104];   // xc half, stride 104
    int w = blockIdx.x;
    int bb = w >> 8, wy = (w >> 4) & 15, wx = w & 15;
    int t = threadIdx.x;
    int lane = t & 63, wv = t >> 6;
    int m = lane & 15, quad = lane >> 4;
    const u16* qw = qvT + (size_t)w * 180 * 256;

    // ---- phase 1: cmap ----
    int ct0 = (wv & 1) * 3, dt0 = (wv >> 1) * 3;
    f32x4 acc[3][3];
    #pragma unroll
    for (int i = 0; i < 3; i++)
        #pragma unroll
        for (int j = 0; j < 3; j++) {
            f32x4 z = {0.f, 0.f, 0.f, 0.f};
            acc[i][j] = z;
        }
    #pragma unroll
    for (int ks = 0; ks < 8; ks++) {
        bf16x8 A[3], B[3];
        #pragma unroll
        for (int i = 0; i < 3; i++)
            A[i] = *(const bf16x8*)(qw + (size_t)((ct0 + i) * 16 + m) * 256 + ks * 32 + quad * 8);
        #pragma unroll
        for (int j = 0; j < 3; j++) {
            int d = (dt0 + j) * 16 + m;
            int dd = d > 89 ? 89 : d;
            B[j] = *(const bf16x8*)(qw + (size_t)(90 + dd) * 256 + ks * 32 + quad * 8);
        }
        #pragma unroll
        for (int i = 0; i < 3; i++)
            #pragma unroll
            for (int j = 0; j < 3; j++)
                acc[i][j] = mfma16(A[i], B[j], acc[i][j]);
    }
    #pragma unroll
    for (int i = 0; i < 3; i++)
        #pragma unroll
        for (int j = 0; j < 3; j++)
            #pragma unroll
            for (int r = 0; r < 4; r++)
                cm[((ct0 + i) * 16 + quad * 4 + r) * 104 + (dt0 + j) * 16 + m] =
                    f2bf(acc[i][j][r] * (1.0f / 256.0f));
    __syncthreads();
    if (t < 96) {   // zero cmap columns 90..95 (pad garbage)
        u32* z = (u32*)(cm + t * 104 + 90);
        z[0] = 0; z[1] = 0; z[2] = 0;
    }
    __syncthreads();

    // ---- phase 2: xc, in two 128-row halves ----
    int base_pix = (bb * 256 + wy * 16) * 256 + wx * 16;
    const __bf16* qwb = (const __bf16*)qw;
    for (int half = 0; half < 2; half++) {
        #pragma unroll
        for (int i = 0; i < 2; i++) {
            int ltl = wv * 2 + i;           // 0..7
            int lt = half * 8 + ltl;
            bf16x8 A[3];
            #pragma unroll
            for (int ks = 0; ks < 3; ks++) {
                const __bf16* colp = qwb + lt * 16 + m;
                #pragma unroll
                for (int j2 = 0; j2 < 8; j2++) {
                    int d = ks * 32 + quad * 8 + j2;
                    int dd = d > 89 ? 89 : d;
                    A[ks][j2] = colp[(size_t)(90 + dd) * 256];
                }
            }
            for (int ct = 0; ct < 6; ct++) {
                f32x4 c4 = {0.f, 0.f, 0.f, 0.f};
                #pragma unroll
                for (int ks = 0; ks < 3; ks++) {
                    bf16x8 B = *(const bf16x8*)(cm + (ct * 16 + m) * 104 + ks * 32 + quad * 8);
                    c4 = mfma16(A[ks], B, c4);
                }
                #pragma unroll
                for (int r = 0; r < 4; r++)
                    xcb[(ltl * 16 + quad * 4 + r) * 104 + ct * 16 + m] = f2bf(c4[r]);
            }
        }
        __syncthreads();
        #pragma unroll
        for (int it = 0; it < 6; it++) {
            int gg = t + it * 256;          // < 1536
            int lrow = gg / 12, seg = gg % 12;
            int l = half * 128 + lrow;
            int pix = base_pix + (l >> 4) * 256 + (l & 15);
            *(uint4*)(yp + (size_t)pix * 192 + 96 + seg * 8) =
                *(const uint4*)(xcb + lrow * 104 + seg * 8);
        }
        __syncthreads();
    }
}

// ---------------------------------------------------------------------------
// K5a: weight prep for MFMA proj: pad proj_w (180x180) to [oc:192][k:192]
//      bf16 hi/lo split, transposed to A-fragment layout [oc][k].
// ---------------------------------------------------------------------------
__global__ __launch_bounds__(256) void k_wprep(const float* __restrict__ pjw,
                                               u16* __restrict__ whiT,
                                               u16* __restrict__ wloT)
{
    int g = blockIdx.x * 256 + threadIdx.x;    // < 36864 = 192*192
    int oc = g / 192, k = g % 192;
    int kp = -1;
    if (k < 90) kp = k;
    else if (k >= 96 && k <= 185) kp = k - 6;
    float v = (kp >= 0 && oc < 180) ? pjw[kp * 180 + oc] : 0.f;
    u16 h = f2bf(v);
    float lo = v - bf2f(h);                    // exact (Sterbenz)
    whiT[g] = h;
    wloT[g] = f2bf(lo);
}

// ---------------------------------------------------------------------------
// K5: y = y_pre @ proj_w + proj_b ; RMSNorm ; + shortcut(x) ; write NCHW fp32
//     NEW: yp B-tile staged to LDS via global_load_lds (streaming 1KB windows)
//     with sigma(o)=o^((o>>3)&7) source permutation so ds_read_b128 fragment
//     reads are 2-way (free).  Kills the 16-line HBM scatter that capped R3
//     at 1.7 TB/s.  st epilogue buffer unions with the staging buffer.
// ---------------------------------------------------------------------------
__global__ __launch_bounds__(256) void k_proj(const u16* __restrict__ yp,
                                              const float* __restrict__ x,
                                              const u16* __restrict__ whiT,
                                              const u16* __restrict__ wloT,
                                              const float* __restrict__ pb,
                                              const float* __restrict__ nw,
                                              float* __restrict__ out)
{
    __shared__ __align__(16) char smem[26112];  // union: yp stage 24576B | st 26112B
    __shared__ float part[4][4][16];
    u16*   ypl = (u16*)smem;
    float* st  = (float*)smem;
    int t = threadIdx.x;
    int lane = t & 63;
    int g = __builtin_amdgcn_readfirstlane(t >> 6);
    int m = lane & 15, q = lane >> 4;
    int pix0 = blockIdx.x * 64;
    int ocbase = g * 48;

    // ---- stage yp tile: 24 x 1KB windows, source-permuted (G21) ----
    const char* ypc = (const char*)(yp + (size_t)pix0 * 192);
    int soff = (lane ^ ((lane >> 3) & 7)) << 4;   // sigma within window
    for (int i = g; i < 24; i += 4) {
        __builtin_amdgcn_global_load_lds(
            (const __attribute__((address_space(1))) void*)(ypc + i * 1024 + soff),
            (__attribute__((address_space(3))) void*)(smem + i * 1024),
            16, 0, 0);
    }
    __syncthreads();

    f32x4 acc[3][4];
    #pragma unroll
    for (int mt = 0; mt < 3; mt++)
        #pragma unroll
        for (int pt = 0; pt < 4; pt++) {
            f32x4 z = {0.f, 0.f, 0.f, 0.f};
            acc[mt][pt] = z;
        }

    int mq = m * 24 + q;    // chunk id component: G = pt*384 + m*24 + ks*4 + q
    #pragma unroll 2
    for (int ks = 0; ks < 6; ks++) {
        bf16x8 B[4];
        #pragma unroll
        for (int pt = 0; pt < 4; pt++) {
            int G = pt * 384 + mq + ks * 4;
            int o = G & 63;
            int slot = (G & ~63) + (o ^ ((o >> 3) & 7));
            B[pt] = *(const bf16x8*)(ypl + slot * 8);
        }
        #pragma unroll
        for (int mt = 0; mt < 3; mt++) {
            bf16x8 Ah = *(const bf16x8*)(whiT + (size_t)(ocbase + mt * 16 + m) * 192 + ks * 32 + q * 8);
            bf16x8 Al = *(const bf16x8*)(wloT + (size_t)(ocbase + mt * 16 + m) * 192 + ks * 32 + q * 8);
            #pragma unroll
            for (int pt = 0; pt < 4; pt++) {
                acc[mt][pt] = mfma16(Ah, B[pt], acc[mt][pt]);
                acc[mt][pt] = mfma16(Al, B[pt], acc[mt][pt]);
            }
        }
    }

    // ---- epilogue: bias, per-pixel RMS ----
    float pbv[3][4], nwv[3][4];
    #pragma unroll
    for (int mt = 0; mt < 3; mt++)
        #pragma unroll
        for (int r = 0; r < 4; r++) {
            int oc = ocbase + mt * 16 + q * 4 + r;
            bool ok = oc < 180;
            pbv[mt][r] = ok ? pb[oc] : 0.f;
            nwv[mt][r] = ok ? nw[oc] : 0.f;
        }
    float ss[4] = {0.f, 0.f, 0.f, 0.f};
    #pragma unroll
    for (int mt = 0; mt < 3; mt++)
        #pragma unroll
        for (int pt = 0; pt < 4; pt++)
            #pragma unroll
            for (int r = 0; r < 4; r++) {
                float y = acc[mt][pt][r] + pbv[mt][r];
                acc[mt][pt][r] = y;
                ss[pt] = fmaf(y, y, ss[pt]);
            }
    #pragma unroll
    for (int pt = 0; pt < 4; pt++) {
        ss[pt] += __shfl_xor(ss[pt], 16);
        ss[pt] += __shfl_xor(ss[pt], 32);
    }
    if (q == 0) {
        #pragma unroll
        for (int pt = 0; pt < 4; pt++) part[g][pt][m] = ss[pt];
    }
    __syncthreads();
    float scale[4];
    #pragma unroll
    for (int pt = 0; pt < 4; pt++) {
        float tot = part[0][pt][m] + part[1][pt][m] + part[2][pt][m] + part[3][pt][m];
        scale[pt] = 1.0f / sqrtf(tot * (1.0f / 180.0f) + 1.1920929e-7f);
    }
    // fold scale*nw into acc (final contribution values)
    #pragma unroll
    for (int mt = 0; mt < 3; mt++)
        #pragma unroll
        for (int pt = 0; pt < 4; pt++)
            #pragma unroll
            for (int r = 0; r < 4; r++)
                acc[mt][pt][r] = acc[mt][pt][r] * scale[pt] * nwv[mt][r];

    // ---- 2-phase LDS transpose; dwordx4 x-load + add + dwordx4 store ----
    // (st aliases the yp staging buffer; all ypl reads completed above)
    int bb = pix0 >> 16, sp0 = pix0 & 65535;
    const float* xb = x + (size_t)bb * 180 * HW + sp0;
    float* ob = out + (size_t)bb * 180 * HW + sp0;
    #pragma unroll
    for (int ph = 0; ph < 2; ph++) {
        if ((g >> 1) == ph) {
            int rb = (g & 1) * 48;
            #pragma unroll
            for (int mt = 0; mt < 3; mt++)
                #pragma unroll
                for (int r = 0; r < 4; r++) {
                    int row = rb + mt * 16 + q * 4 + r;
                    #pragma unroll
                    for (int pt = 0; pt < 4; pt++)
                        st[row * 68 + pt * 16 + m] = acc[mt][pt][r];
                }
        }
        __syncthreads();
        int nch = ph ? 1344 : 1536;        // rows*16 (phase B: oc 96..179)
        for (int i = t; i < nch; i += 256) {
            int row = i >> 4, j = i & 15;
            int oc = ph * 96 + row;
            f32x4 d = *(const f32x4*)(st + row * 68 + j * 4);
            size_t off = (size_t)oc * HW + j * 4;
            f32x4 xv = *(const f32x4*)(xb + off);
            *(f32x4*)(ob + off) = d + xv;
        }
        __syncthreads();
    }
}

// ---------------------------------------------------------------------------
extern "C" void kernel_launch(void* const* d_in, const int* in_sizes, int n_in,
                              void* d_out, int out_size, void* d_ws, size_t ws_size,
                              hipStream_t stream)
{
    const float* x    = (const float*)d_in[0];
    const float* w1   = (const float*)d_in[1];
    const float* b1   = (const float*)d_in[2];
    const float* w2   = (const float*)d_in[3];
    const float* b2   = (const float*)d_in[4];
    const float* w3   = (const float*)d_in[5];
    const float* b3   = (const float*)d_in[6];
    const float* lw   = (const float*)d_in[7];
    const float* lb   = (const float*)d_in[8];
    const float* slw  = (const float*)d_in[9];
    const float* slb  = (const float*)d_in[10];
    const float* pw   = (const float*)d_in[11];
    const float* pb   = (const float*)d_in[12];
    const float* ln1w = (const float*)d_in[13];
    const float* ln1b = (const float*)d_in[14];
    const float* l1w  = (const float*)d_in[15];
    const float* l1b  = (const float*)d_in[16];
    const float* ln2w = (const float*)d_in[17];
    const float* ln2b = (const float*)d_in[18];
    const float* l2w  = (const float*)d_in[19];
    const float* l2b  = (const float*)d_in[20];
    const float* ln3w = (const float*)d_in[21];
    const float* ln3b = (const float*)d_in[22];
    const float* l3w  = (const float*)d_in[23];
    const float* l3b  = (const float*)d_in[24];
    const float* pjw  = (const float*)d_in[25];
    const float* pjb  = (const float*)d_in[26];
    const float* nw   = (const float*)d_in[27];
    float* out = (float*)d_out;

    char* ws = (char*)d_ws;
    // layout (time-disjoint overlap: qvT reuses dead h1 region; whiT/wloT
    // reuse dead h2 region after k_gate; gate weights live at the head of the
    // yp region, which is only written by k_spat/k_chan AFTER k_gate is done)
    float* pos = (float*)(ws + 0);            // 23 KB
    float* rpb = (float*)(ws + 24576);        // 384 KB  -> end 417792
    u16*  h2  = (u16*)(ws + 417792);          // 18.87 MB -> end 19292160
    u16*  whiT = (u16*)(ws + 417792);         // 72 KB (written AFTER k_gate)
    u16*  wloT = (u16*)(ws + 417792 + 73728); // 72 KB
    u16*  h1  = (u16*)(ws + 19292160);        // 18.87 MB -> end 38166528 (dead after conv3)
    u16*  qvT = (u16*)(ws + 19292160);        // 94.37 MB -> end 113664000 (written in k_gate)
    u16*  yp  = (u16*)(ws + 113664000);       // 100.66 MB -> end 214327296
    u16*  gwh = (u16*)(ws + 113664000);            // 73728 B  (dead once k_spat runs)
    u16*  gwl = (u16*)(ws + 113664000 + 73728);    // 73728 B
    u16*  cwh = (u16*)(ws + 113664000 + 147456);   // 24576 B
    u16*  cwl = (u16*)(ws + 113664000 + 172032);   // 24576 B -> end 113860608
    // total ws use: ~214.3 MB

    k_wgprep<<<dim3(192), dim3(256), 0, stream>>>(lw, w3, gwh, gwl, cwh, cwl);
    k_pos<<<dim3(1), dim3(1024), 0, stream>>>(pw, pb, ln1w, ln1b, l1w, l1b,
                                              ln2w, ln2b, l2w, l2b, ln3w, ln3b,
                                              l3w, l3b, pos);
    k_rpb<<<dim3(384), dim3(256), 0, stream>>>(pos, rpb);
    k_conv1<<<dim3(1024), dim3(256), 0, stream>>>(x, w1, b1, h1);
    k_conv3<<<dim3(16, 16, 4), dim3(16, 16), 0, stream>>>(h1, w2, b2, h2);
    k_gate<<<dim3(4096), dim3(256), 0, stream>>>(h2, x, gwh, gwl, cwh, cwl,
                                                 b3, lb, qvT);
    k_wprep<<<dim3(144), dim3(256), 0, stream>>>(pjw, whiT, wloT);   // h2 dead now
    k_spat<<<dim3(1024), dim3(256), 0, stream>>>(qvT, rpb, slw, slb, yp);
    k_chan<<<dim3(1024), dim3(256), 0, stream>>>(qvT, yp);
    k_proj<<<dim3(4096), dim3(256), 0, stream>>>(yp, x, whiT, wloT, pjb, nw, out);
}